// Round 17
// baseline (423.173 us; speedup 1.0000x reference)
//
#include <hip/hip_runtime.h>
#include <stdint.h>

// Problem constants (fixed-size problem)
#define DM   512
#define DFF  2048
#define NH   8
#define EH   64
#define SEQ  2048
#define NBAT 2
#define NTOK (NBAT*SEQ)   // 4096
#define LOG2E 1.44269504088896340736f

typedef __attribute__((ext_vector_type(8))) short  s16x8;
typedef __attribute__((ext_vector_type(8))) __bf16 bf16x8;
typedef __attribute__((ext_vector_type(4))) float  f32x4;

__device__ __forceinline__ short f2bf(float f) {
  union { float f; unsigned int i; } c; c.f = f;
  unsigned int x = c.i;
  x += 0x7fffu + ((x >> 16) & 1u);   // RNE
  return (short)(x >> 16);
}
__device__ __forceinline__ float bf2f(short u) {
  union { unsigned int i; float f; } c;
  c.i = ((unsigned int)(unsigned short)u) << 16;
  return c.f;
}
__device__ __forceinline__ f32x4 mfma16(bf16x8 a, bf16x8 b, f32x4 c) {
  return __builtin_amdgcn_mfma_f32_16x16x32_bf16(a, b, c, 0, 0, 0);
}
// Async global->LDS, 16B per lane. LDS dest = wave-uniform base + lane*16.
__device__ __forceinline__ void gl_lds16(const short* g, short* l) {
  __builtin_amdgcn_global_load_lds(
      (const __attribute__((address_space(1))) unsigned int*)(const void*)g,
      (__attribute__((address_space(3))) unsigned int*)(void*)l, 16, 0, 0);
}

__global__ __launch_bounds__(256) void fill_code_f32(float* __restrict__ out,
                                                     float code)
{
  out[blockIdx.x * 256 + threadIdx.x] = code;
}

// ---------------------------------------------------------------------------
// Fused prep: blocks [0,3072) transpose+cast weights; blocks [3072,11264)
// cast x -> f32 residual copy + bf16 GEMM operand.
// ---------------------------------------------------------------------------
__global__ __launch_bounds__(256) void prep_all(
    const float* __restrict__ Wq, const float* __restrict__ Wk,
    const float* __restrict__ Wv, const float* __restrict__ Wo,
    const float* __restrict__ W1, const float* __restrict__ W2,
    short* __restrict__ Wqkvt, short* __restrict__ Wot,
    short* __restrict__ W1t,   short* __restrict__ W2t,
    const float* __restrict__ x, float* __restrict__ sumf,
    short* __restrict__ x16)
{
  if (blockIdx.x >= 3072) {             // cast path
    int i = (blockIdx.x - 3072) * 256 + threadIdx.x;
    float v = x[i];
    sumf[i] = v;
    x16[i]  = f2bf(v);
    return;
  }
  int gw   = blockIdx.x * 4 + (threadIdx.x >> 6);
  int lane = threadIdx.x & 63;
  int l = gw / 6144;
  int g = gw % 6144;
  const float* src; short* dst; int K, N, gi;
  if (g < 2048) {                       // Wq,Wk,Wv,Wo  (512x512 each)
    int w = g >> 9; gi = g & 511; K = 512; N = 512;
    src = (w == 0 ? Wq : w == 1 ? Wk : w == 2 ? Wv : Wo) + l * 262144;
    dst = (w < 3) ? (Wqkvt + l * 786432 + w * 262144) : (Wot + l * 262144);
  } else if (g < 4096) {                // W1 (512 x 2048)
    gi = g - 2048; K = 512; N = 2048;
    src = W1 + l * 1048576; dst = W1t + l * 1048576;
  } else {                              // W2 (2048 x 512)
    gi = g - 4096; K = 2048; N = 512;
    src = W2 + l * 1048576; dst = W2t + l * 1048576;
  }
  int nb = N >> 6;
  int n  = (gi % nb) * 64 + lane;
  int k0 = (gi / nb) * 8;
  s16x8 v;
  #pragma unroll
  for (int i = 0; i < 8; i++) v[i] = f2bf(src[(size_t)(k0 + i) * N + n]);
  *(s16x8*)(dst + (size_t)n * K + k0) = v;
}

// ---------------------------------------------------------------------------
// Fused split-K reduce + LayerNorm. One wave per row (D=512, 8 elems/lane).
// t = sum_p(bf16 parts[p]) + bias + resid (rf f32 | rb bf16)
// mode 0 (O-proj): sumf = t          ; outb = bf16(LN(t))   (xb for FFN)
// mode 1 (FFN2)  : sumf = LN(t) (f32); outb = bf16(LN(t))   (next-layer x)
// ---------------------------------------------------------------------------
__global__ __launch_bounds__(256) void skred_ln(
    const short* __restrict__ parts, const float* __restrict__ bias,
    const float* __restrict__ rf, const short* __restrict__ rb,
    const float* __restrict__ g, const float* __restrict__ bb,
    float* __restrict__ sumf, short* __restrict__ outb, int mode)
{
  const int row  = blockIdx.x * 4 + (threadIdx.x >> 6);
  const int lane = threadIdx.x & 63;
  const int col  = lane * 8;
  const size_t base = (size_t)row * DM + col;
  float t[8];
  #pragma unroll
  for (int j = 0; j < 8; j++) t[j] = bias[col + j];
  #pragma unroll
  for (int p = 0; p < 4; p++) {
    s16x8 v = *(const s16x8*)(parts + (size_t)p * (NTOK * DM) + base);
    #pragma unroll
    for (int j = 0; j < 8; j++) t[j] += bf2f(v[j]);
  }
  if (mode == 0) {
    #pragma unroll
    for (int j = 0; j < 8; j++) t[j] += rf[base + j];
  } else {
    s16x8 v = *(const s16x8*)(rb + base);
    #pragma unroll
    for (int j = 0; j < 8; j++) t[j] += bf2f(v[j]);
  }
  float s = 0.f, ss = 0.f;
  #pragma unroll
  for (int j = 0; j < 8; j++) { s += t[j]; ss += t[j] * t[j]; }
  #pragma unroll
  for (int off = 32; off > 0; off >>= 1) {
    s += __shfl_xor(s, off); ss += __shfl_xor(ss, off);
  }
  float mean = s * (1.f / DM);
  float var  = ss * (1.f / DM) - mean * mean;
  float rstd = rsqrtf(var + 1e-5f);
  if (mode == 0) {
    #pragma unroll
    for (int j = 0; j < 8; j++) {
      sumf[base + j] = t[j];
      outb[base + j] = f2bf((t[j] - mean) * rstd * g[col + j] + bb[col + j]);
    }
  } else {
    #pragma unroll
    for (int j = 0; j < 8; j++) {
      float y = (t[j] - mean) * rstd * g[col + j] + bb[col + j];
      sumf[base + j] = y;
      outb[base + j] = f2bf(y);
    }
  }
}

// ---------------------------------------------------------------------------
// GEMM: C(M,N) = A(M,K) @ W, W pre-transposed Bt(N,K). bf16 MFMA.
// Tile TM x 128, BK=64 staged as two stride-32 halves per barrier pair.
// Optional split-K (KS chunks, deterministic bf16 partials).
// Modes: 0=QKV scatter, 2=GELU->bf16, 4=bf16 partial write.
// ---------------------------------------------------------------------------
template<int TM>
__global__ __launch_bounds__(256) void gemm_bt(
    const short* __restrict__ A, const short* __restrict__ Bt,
    int M, int N, int K, int KS, int mode,
    const float* __restrict__ bq, const float* __restrict__ bk,
    const float* __restrict__ bv,
    short* __restrict__ oq, short* __restrict__ okk, short* __restrict__ ov)
{
  __shared__ short As[2][TM * 32];     // two K-halves, proven layout each
  __shared__ short Bs[2][128 * 32];
  constexpr int MT = TM / 32;          // 16-row tiles per wave (4 or 2)
  const int tid  = threadIdx.x;
  const int lane = tid & 63;
  const int wid  = tid >> 6;
  const int lm   = lane & 15, quad = lane >> 4;
  const int nbn  = N >> 7;
  const int nb2  = (M / TM) * nbn;
  const int ks   = blockIdx.x / nb2;
  const int rem  = blockIdx.x % nb2;
  const int m0   = (rem / nbn) * TM;
  const int n0   = (rem % nbn) << 7;
  const int wm   = (wid & 1) * (TM / 2), wn = (wid >> 1) * 64;
  const int Kc   = K / KS;
  const int kbeg = ks * Kc;

  f32x4 acc[MT][4];
  #pragma unroll
  for (int i = 0; i < MT; i++)
    #pragma unroll
    for (int j = 0; j < 4; j++) acc[i][j] = (f32x4){0.f, 0.f, 0.f, 0.f};

  const short* Abase = A  + (size_t)m0 * K;
  const short* Bbase = Bt + (size_t)n0 * K;

  for (int k0 = kbeg; k0 < kbeg + Kc; k0 += 64) {
    __syncthreads();                     // prior iteration's LDS reads done
    #pragma unroll
    for (int half = 0; half < 2; half++) {
      const int kk = k0 + half * 32;
      #pragma unroll
      for (int j = 0; j < TM / 64; j++) {  // As half: TM*4 chunks of 16B
        int c = j * 256 + wid * 64 + lane;
        gl_lds16(Abase + (size_t)(c >> 2) * K + kk + (c & 3) * 8,
                 &As[half][(j * 256 + wid * 64) * 8]);
      }
      #pragma unroll
      for (int j = 0; j < 2; j++) {        // Bs half: 512 chunks
        int c = j * 256 + wid * 64 + lane;
        gl_lds16(Bbase + (size_t)(c >> 2) * K + kk + (c & 3) * 8,
                 &Bs[half][(j * 256 + wid * 64) * 8]);
      }
    }
    __syncthreads();                     // drains vmcnt -> tiles in LDS
    #pragma unroll
    for (int half = 0; half < 2; half++) {
      bf16x8 af[MT], bfr[4];
      #pragma unroll
      for (int t = 0; t < MT; t++)
        af[t] = *(const bf16x8*)&As[half][(wm + t * 16 + lm) * 32 + quad * 8];
      #pragma unroll
      for (int t = 0; t < 4; t++)
        bfr[t] = *(const bf16x8*)&Bs[half][(wn + t * 16 + lm) * 32 + quad * 8];
      #pragma unroll
      for (int mt = 0; mt < MT; mt++)
        #pragma unroll
        for (int nt = 0; nt < 4; nt++)
          acc[mt][nt] = mfma16(af[mt], bfr[nt], acc[mt][nt]);
    }
  }

  #pragma unroll
  for (int mt = 0; mt < MT; mt++) {
    int row = m0 + wm + mt * 16 + quad * 4;
    #pragma unroll
    for (int nt = 0; nt < 4; nt++) {
      int col = n0 + wn + nt * 16 + lm;
      f32x4 v = acc[mt][nt];
      if (mode == 0) {                       // QKV scatter, N=1536
        int which = col >> 9; int d = col & 511;
        int hh = d >> 6; int e = d & 63;
        const float* bias = which == 0 ? bq : which == 1 ? bk : bv;
        float bb = bias[d];
        #pragma unroll
        for (int r = 0; r < 4; r++) {
          int tok = row + r; int bI = tok >> 11, li = tok & 2047;
          float val = v[r] + bb;
          if (which == 0)
            oq [(((size_t)bI * NH + hh) * SEQ + li) * EH + e] = f2bf(val);
          else if (which == 1)
            okk[(((size_t)bI * NH + hh) * SEQ + li) * EH + e] = f2bf(val);
          else
            ov [(((size_t)bI * NH + hh) * EH + e) * SEQ + li] = f2bf(val);
        }
      } else if (mode == 2) {                // GELU -> bf16
        float bb = bq[col];
        #pragma unroll
        for (int r = 0; r < 4; r++) {
          float x = v[r] + bb;
          float u = 0.7978845608f * (x + 0.044715f * x * x * x);
          float t = 1.f - 2.f / (1.f + __expf(2.f * u));   // tanh, safe
          size_t idx = (size_t)(row + r) * N + col;
          oq[idx] = f2bf(0.5f * x * (1.f + t));
        }
      } else {                               // mode 4: bf16 split-K partial
        short* op = oq + (size_t)ks * M * N;
        #pragma unroll
        for (int r = 0; r < 4; r++)
          op[(size_t)(row + r) * N + col] = f2bf(v[r]);
      }
    }
  }
}

// ---------------------------------------------------------------------------
// Attention subtile: QK^T (16q x 64k) -> fixed-bias softmax (truncated P)
// -> PV accumulate. Inner math identical to harness-proven v7b.
// ---------------------------------------------------------------------------
__device__ __forceinline__ void do_subtile(
    bf16x8 qf0, bf16x8 qf1,
    const short* __restrict__ Ks, const short* __restrict__ Vs,
    short* __restrict__ Psw, const float* dl, float st2,
    int s0, int rowq0, bool diag,
    float* lr, f32x4* O, int lm, int quad)
{
  f32x4 S[4];
  #pragma unroll
  for (int nt = 0; nt < 4; nt++) {
    S[nt] = (f32x4){0.f, 0.f, 0.f, 0.f};
    S[nt] = mfma16(qf0, *(const bf16x8*)&Ks[(nt*16 + lm) * 72 + quad * 8], S[nt]);
    S[nt] = mfma16(qf1, *(const bf16x8*)&Ks[(nt*16 + lm) * 72 + 32 + quad * 8], S[nt]);
  }
  #pragma unroll
  for (int r = 0; r < 4; r++) {
    float sc[4];
    #pragma unroll
    for (int nt = 0; nt < 4; nt++) sc[nt] = fmaf(st2, S[nt][r], dl[nt]);
    if (diag) {
      int rowq = rowq0 + quad * 4 + r;
      #pragma unroll
      for (int nt = 0; nt < 4; nt++)
        if (s0 + nt * 16 + lm > rowq) sc[nt] = -__builtin_inff();
    }
    unsigned int u0 = __float_as_uint(exp2f(sc[0]));
    unsigned int u1 = __float_as_uint(exp2f(sc[1]));
    unsigned int u2 = __float_as_uint(exp2f(sc[2]));
    unsigned int u3 = __float_as_uint(exp2f(sc[3]));
    lr[r] += (__uint_as_float(u0 & 0xffff0000u) +
              __uint_as_float(u1 & 0xffff0000u)) +
             (__uint_as_float(u2 & 0xffff0000u) +
              __uint_as_float(u3 & 0xffff0000u));
    short* pr = &Psw[(quad * 4 + r) * 72];
    pr[lm]      = (short)(u0 >> 16);
    pr[16 + lm] = (short)(u1 >> 16);
    pr[32 + lm] = (short)(u2 >> 16);
    pr[48 + lm] = (short)(u3 >> 16);
  }
  bf16x8 pf0 = *(const bf16x8*)&Psw[lm * 72 + quad * 8];
  bf16x8 pf1 = *(const bf16x8*)&Psw[lm * 72 + 32 + quad * 8];
  #pragma unroll
  for (int et = 0; et < 4; et++) {
    O[et] = mfma16(pf0, *(const bf16x8*)&Vs[(et*16 + lm) * 72 + quad * 8], O[et]);
    O[et] = mfma16(pf1, *(const bf16x8*)&Vs[(et*16 + lm) * 72 + 32 + quad * 8], O[et]);
  }
}

// ---------------------------------------------------------------------------
// Flash attention v8: 128-query tiles (each wave owns two 16-q subtiles)
// sharing one staged 64-key K/V tile -> staging + barriers per unit work
// halved vs v7. Fixed-bias softmax + 4-way key split (both proven).
// ---------------------------------------------------------------------------
__global__ __launch_bounds__(256) void attn_v8(
    const short* __restrict__ Q, const short* __restrict__ Kg,
    const short* __restrict__ Vt,
    const float* __restrict__ tau, const float* __restrict__ delta,
    short* __restrict__ opart, float* __restrict__ lpart)
{
  __shared__ short Ks[64 * 72];       // [key][e]
  __shared__ short Vs[64 * 72];       // [e][key]
  __shared__ short Ps[4][16 * 72];    // per-wave P scratch [q][key]
  const int tid  = threadIdx.x;
  const int lane = tid & 63, wid = tid >> 6;
  const int lm = lane & 15, quad = lane >> 4;
  const int tile = blockIdx.x >> 2;   // 0..255 = bh*16 + (15-tt)
  const int part = blockIdx.x & 3;    // key quarter
  const int tt = 15 - (tile & 15);    // reversed: big-work blocks first
  const int bh = tile >> 4;
  const int b  = bh >> 3;
  const int q0 = tt * 128;
  const int qA = q0 + wid * 16;       // low-half subtile rows
  const int qB = q0 + 64 + wid * 16;  // high-half subtile rows
  const size_t bhq = (size_t)bh * SEQ;
  const short* kbase = Kg + bhq * EH;
  const short* vbase = Vt + (size_t)bh * (EH * SEQ);

  const int nblk = 2 * tt + 2;
  const int kb0 = (nblk * part) >> 2;
  const int kb1 = (nblk * (part + 1)) >> 2;

  bf16x8 qfA0 = *(const bf16x8*)(Q + (bhq + qA + lm) * EH + quad * 8);
  bf16x8 qfA1 = *(const bf16x8*)(Q + (bhq + qA + lm) * EH + 32 + quad * 8);
  bf16x8 qfB0 = *(const bf16x8*)(Q + (bhq + qB + lm) * EH + quad * 8);
  bf16x8 qfB1 = *(const bf16x8*)(Q + (bhq + qB + lm) * EH + 32 + quad * 8);

  const float st2 = 0.125f * LOG2E * tau[b];
  f32x4 OA[4], OB[4];
  #pragma unroll
  for (int i = 0; i < 4; i++) {
    OA[i] = (f32x4){0.f, 0.f, 0.f, 0.f};
    OB[i] = (f32x4){0.f, 0.f, 0.f, 0.f};
  }
  float lrA[4] = {0.f, 0.f, 0.f, 0.f};
  float lrB[4] = {0.f, 0.f, 0.f, 0.f};

  const int r0 = tid >> 3,         ch0 = (tid & 7) * 8;
  const int r1 = (tid + 256) >> 3, ch1 = (tid & 7) * 8;

  for (int kb = kb0; kb < kb1; kb++) {
    const int s0 = kb << 6;
    s16x8 ka  = *(const s16x8*)(kbase + (size_t)(s0 + r0) * EH + ch0);
    s16x8 kb_ = *(const s16x8*)(kbase + (size_t)(s0 + r1) * EH + ch1);
    s16x8 va  = *(const s16x8*)(vbase + (size_t)r0 * SEQ + s0 + ch0);
    s16x8 vb  = *(const s16x8*)(vbase + (size_t)r1 * SEQ + s0 + ch1);
    __syncthreads();                  // prior iteration's LDS reads done
    *(s16x8*)&Ks[r0 * 72 + ch0] = ka;
    *(s16x8*)&Ks[r1 * 72 + ch1] = kb_;
    *(s16x8*)&Vs[r0 * 72 + ch0] = va;
    *(s16x8*)&Vs[r1 * 72 + ch1] = vb;
    __syncthreads();

    float dl[4];
    #pragma unroll
    for (int nt = 0; nt < 4; nt++)    // delta in log2 domain, minus fixed M=8
      dl[nt] = fmaf(0.125f * LOG2E, delta[(size_t)b * SEQ + s0 + nt * 16 + lm],
                    -8.f);

    if (kb <= 2 * tt)                 // wave-uniform (block-uniform) branch
      do_subtile(qfA0, qfA1, Ks, Vs, Ps[wid], dl, st2, s0, qA,
                 kb == 2 * tt, lrA, OA, lm, quad);
    do_subtile(qfB0, qfB1, Ks, Vs, Ps[wid], dl, st2, s0, qB,
               kb == 2 * tt + 1, lrB, OB, lm, quad);
  }

  // Reduce lr across the 16 lanes of each row group (once).
  #pragma unroll
  for (int r = 0; r < 4; r++) {
    float sA = lrA[r], sB = lrB[r];
    #pragma unroll
    for (int off = 1; off < 16; off <<= 1) {
      sA += __shfl_xor(sA, off); sB += __shfl_xor(sB, off);
    }
    lrA[r] = sA; lrB[r] = sB;
  }

  // Write partials: O (bf16) to opart[slot] (128q x 64e), l (f32) 128/slot.
  const int slot = (tile << 2) | part;
  short* ob = opart + (size_t)slot * 8192;
  float* lb = lpart + (size_t)slot * 128;
  #pragma unroll
  for (int r = 0; r < 4; r++) {
    int ql = wid * 16 + quad * 4 + r;
    #pragma unroll
    for (int et = 0; et < 4; et++) {
      ob[ql * 64 + et * 16 + lm]        = f2bf(OA[et][r]);
      ob[(64 + ql) * 64 + et * 16 + lm] = f2bf(OB[et][r]);
    }
    if (lm == 0) { lb[ql] = lrA[r]; lb[64 + ql] = lrB[r]; }
  }
}

// Combine the 4 key-quarter partials, normalize, write bf16 at16 (B*L, D).
__global__ __launch_bounds__(256) void attn_reduce(
    const short* __restrict__ opart, const float* __restrict__ lpart,
    short* __restrict__ Oa)
{
  const int t = blockIdx.x;           // 0..255, matches attn_v8 tile mapping
  const int tt = 15 - (t & 15);
  const int bh = t >> 4;
  const int b  = bh >> 3, h = bh & 7;
  const int q0 = tt * 128;
  #pragma unroll
  for (int i = 0; i < 32; i++) {
    int idx = i * 256 + threadIdx.x;  // 0..8191
    int q = idx >> 6, e = idx & 63;
    float l = 0.f, o = 0.f;
    #pragma unroll
    for (int p = 0; p < 4; p++) {
      int slot = t * 4 + p;
      l += lpart[(size_t)slot * 128 + q];
      o += bf2f(opart[(size_t)slot * 8192 + idx]);
    }
    Oa[((size_t)b * SEQ + q0 + q) * DM + h * EH + e] = f2bf(o / l);
  }
}

// ---------------------------------------------------------------------------
// LayerNorm over D=512. One wave per row. (Final LN only.)
// ---------------------------------------------------------------------------
__global__ __launch_bounds__(256) void ln_kernel(
    const float* in, const float* __restrict__ g, const float* __restrict__ bb,
    float* outf, short* outb)
{
  int row  = blockIdx.x * 4 + (threadIdx.x >> 6);
  int lane = threadIdx.x & 63;
  const float* p = in + (size_t)row * DM;
  float v[8]; float s = 0.f, ss = 0.f;
  #pragma unroll
  for (int i = 0; i < 8; i++) {
    float x = p[lane + i * 64]; v[i] = x; s += x; ss += x * x;
  }
  #pragma unroll
  for (int off = 32; off > 0; off >>= 1) {
    s += __shfl_xor(s, off); ss += __shfl_xor(ss, off);
  }
  float mean = s * (1.f / DM);
  float var  = ss * (1.f / DM) - mean * mean;
  float rstd = rsqrtf(var + 1e-5f);
  #pragma unroll
  for (int i = 0; i < 8; i++) {
    int c = lane + i * 64;
    float y = (v[i] - mean) * rstd * g[c] + bb[c];
    if (outf) outf[(size_t)row * DM + c] = y;
    if (outb) outb[(size_t)row * DM + c] = f2bf(y);
  }
}

// ---------------------------------------------------------------------------
extern "C" void kernel_launch(void* const* d_in, const int* in_sizes, int n_in,
                              void* d_out, int out_size, void* d_ws, size_t ws_size,
                              hipStream_t stream)
{
  float* out = (float*)d_out;          // f32 output

  if (ws_size < (size_t)62918656) {    // 60 MB + safety
    fill_code_f32<<<2097152 / 256, 256, 0, stream>>>(
        out, 1200.f + (float)(ws_size >> 20));
    return;
  }

  const float* x    = (const float*)d_in[0];
  const float* tau  = (const float*)d_in[1];
  const float* del  = (const float*)d_in[2];
  const float* Wq = (const float*)d_in[4];
  const float* bq = (const float*)d_in[5];
  const float* Wk = (const float*)d_in[6];
  const float* bk = (const float*)d_in[7];
  const float* Wv = (const float*)d_in[8];
  const float* bv = (const float*)d_in[9];
  const float* Wo = (const float*)d_in[10];
  const float* bo = (const float*)d_in[11];
  const float* W1 = (const float*)d_in[12];
  const float* b1 = (const float*)d_in[13];
  const float* W2 = (const float*)d_in[14];
  const float* b2 = (const float*)d_in[15];
  const float* ln1g = (const float*)d_in[16];
  const float* ln1b = (const float*)d_in[17];
  const float* ln2g = (const float*)d_in[18];
  const float* ln2b = (const float*)d_in[19];
  const float* lnfg = (const float*)d_in[20];
  const float* lnfb = (const float*)d_in[21];

  char* ws = (char*)d_ws;
  float* sumf  = (float*)(ws + 0);          //  8 MB  fp32 residual chain (x)
  short* x16   = (short*)(ws + 8388608);    //  4 MB  bf16 x (GEMM A operand)
  short* xb16  = (short*)(ws + 12582912);   //  4 MB  LN1 out (xb)
  short* q16   = (short*)(ws + 16777216);   //  4 MB  (B,H,L,E)
  short* k16   = (short*)(ws + 20971520);   //  4 MB  (B,H,L,E)
  short* vt16  = (short*)(ws + 25165824);   //  4 MB  (B,H,E,L)
  short* at16  = (short*)(ws + 29360128);   //  4 MB  attention out (B*L, D)
  short* h16   = (short*)(ws + 33554432);   // 16 MB  FFN hidden
  short* Wqkvt = (short*)(ws + 50331648);   //  3 MB
  short* Wot   = (short*)(ws + 53477376);   //  1 MB
  short* W1t   = (short*)(ws + 54525952);   //  4 MB
  short* W2t   = (short*)(ws + 58720256);   //  4 MB  (total 60 MB)
  // Overlays (regions dead at time of use):
  short* aopart = (short*)(ws + 33554432);  // attn O partials (h16, 16 MB)
  float* alpart = (float*)(ws + 12582912);  // attn l partials (xb16, 512 KB)
  short* oppart = (short*)(ws + 33554432);  // O-proj split-K partials (h16)
  short* f2part = (short*)(ws + 16777216);  // FFN2 split-K partials
                                            //   (q16..at16, 16 MB)

  prep_all<<<11264, 256, 0, stream>>>(Wq, Wk, Wv, Wo, W1, W2,
                                      Wqkvt, Wot, W1t, W2t, x, sumf, x16);

  for (int l = 0; l < 2; l++) {
    // QKV (N=1536, K=512) -- TM=64: 768 blocks, 8 BK=64 iters
    gemm_bt<64><<<64 * 12, 256, 0, stream>>>(x16, Wqkvt + l * 786432,
        NTOK, 3 * DM, DM, 1, 0,
        bq + l * DM, bk + l * DM, bv + l * DM,
        q16, k16, vt16);
    attn_v8<<<4 * 256, 256, 0, stream>>>(
        q16, k16, vt16, tau, del, aopart, alpart);
    attn_reduce<<<256, 256, 0, stream>>>(aopart, alpart, at16);
    // O-proj: split-K x4 -> fused reduce + residual + LN1 (xb16)
    gemm_bt<64><<<64 * 4 * 4, 256, 0, stream>>>(at16, Wot + l * 262144,
        NTOK, DM, DM, 4, 4,
        nullptr, nullptr, nullptr,
        oppart, nullptr, nullptr);
    skred_ln<<<1024, 256, 0, stream>>>(oppart, bo + l * DM, sumf, nullptr,
        ln1g + l * DM, ln1b + l * DM, sumf, xb16, 0);
    // FFN1 + GELU (N=2048, K=512) -- TM=64: 1024 blocks, 8 BK=64 iters
    gemm_bt<64><<<64 * 16, 256, 0, stream>>>(xb16, W1t + l * 1048576,
        NTOK, DFF, DM, 1, 2,
        b1 + l * DFF, nullptr, nullptr,
        h16, nullptr, nullptr);
    // FFN2: split-K x4 -> fused reduce + xb residual + LN2 (sumf + x16)
    gemm_bt<64><<<64 * 4 * 4, 256, 0, stream>>>(h16, W2t + l * 1048576,
        NTOK, DM, DFF, 4, 4,
        nullptr, nullptr, nullptr,
        f2part, nullptr, nullptr);
    skred_ln<<<1024, 256, 0, stream>>>(f2part, b2 + l * DM, nullptr, xb16,
        ln2g + l * DM, ln2b + l * DM, sumf, x16, 1);
  }
  ln_kernel<<<NTOK / 4, 256, 0, stream>>>(sumf, lnfg, lnfb, out, nullptr);
}

// Round 18
// 410.884 us; speedup vs baseline: 1.0299x; 1.0299x over previous
//
#include <hip/hip_runtime.h>
#include <stdint.h>

// Problem constants (fixed-size problem)
#define DM   512
#define DFF  2048
#define NH   8
#define EH   64
#define SEQ  2048
#define NBAT 2
#define NTOK (NBAT*SEQ)   // 4096
#define LOG2E 1.44269504088896340736f

typedef __attribute__((ext_vector_type(8))) short  s16x8;
typedef __attribute__((ext_vector_type(8))) __bf16 bf16x8;
typedef __attribute__((ext_vector_type(4))) float  f32x4;

__device__ __forceinline__ short f2bf(float f) {
  union { float f; unsigned int i; } c; c.f = f;
  unsigned int x = c.i;
  x += 0x7fffu + ((x >> 16) & 1u);   // RNE
  return (short)(x >> 16);
}
__device__ __forceinline__ float bf2f(short u) {
  union { unsigned int i; float f; } c;
  c.i = ((unsigned int)(unsigned short)u) << 16;
  return c.f;
}
__device__ __forceinline__ f32x4 mfma16(bf16x8 a, bf16x8 b, f32x4 c) {
  return __builtin_amdgcn_mfma_f32_16x16x32_bf16(a, b, c, 0, 0, 0);
}
// Async global->LDS, 16B per lane. LDS dest = wave-uniform base + lane*16.
__device__ __forceinline__ void gl_lds16(const short* g, short* l) {
  __builtin_amdgcn_global_load_lds(
      (const __attribute__((address_space(1))) unsigned int*)(const void*)g,
      (__attribute__((address_space(3))) unsigned int*)(void*)l, 16, 0, 0);
}

__global__ __launch_bounds__(256) void fill_code_f32(float* __restrict__ out,
                                                     float code)
{
  out[blockIdx.x * 256 + threadIdx.x] = code;
}

// ---------------------------------------------------------------------------
// Fused prep: blocks [0,3072) transpose+cast weights; blocks [3072,11264)
// cast x -> f32 residual copy + bf16 GEMM operand.
// ---------------------------------------------------------------------------
__global__ __launch_bounds__(256) void prep_all(
    const float* __restrict__ Wq, const float* __restrict__ Wk,
    const float* __restrict__ Wv, const float* __restrict__ Wo,
    const float* __restrict__ W1, const float* __restrict__ W2,
    short* __restrict__ Wqkvt, short* __restrict__ Wot,
    short* __restrict__ W1t,   short* __restrict__ W2t,
    const float* __restrict__ x, float* __restrict__ sumf,
    short* __restrict__ x16)
{
  if (blockIdx.x >= 3072) {             // cast path
    int i = (blockIdx.x - 3072) * 256 + threadIdx.x;
    float v = x[i];
    sumf[i] = v;
    x16[i]  = f2bf(v);
    return;
  }
  int gw   = blockIdx.x * 4 + (threadIdx.x >> 6);
  int lane = threadIdx.x & 63;
  int l = gw / 6144;
  int g = gw % 6144;
  const float* src; short* dst; int K, N, gi;
  if (g < 2048) {                       // Wq,Wk,Wv,Wo  (512x512 each)
    int w = g >> 9; gi = g & 511; K = 512; N = 512;
    src = (w == 0 ? Wq : w == 1 ? Wk : w == 2 ? Wv : Wo) + l * 262144;
    dst = (w < 3) ? (Wqkvt + l * 786432 + w * 262144) : (Wot + l * 262144);
  } else if (g < 4096) {                // W1 (512 x 2048)
    gi = g - 2048; K = 512; N = 2048;
    src = W1 + l * 1048576; dst = W1t + l * 1048576;
  } else {                              // W2 (2048 x 512)
    gi = g - 4096; K = 2048; N = 512;
    src = W2 + l * 1048576; dst = W2t + l * 1048576;
  }
  int nb = N >> 6;
  int n  = (gi % nb) * 64 + lane;
  int k0 = (gi / nb) * 8;
  s16x8 v;
  #pragma unroll
  for (int i = 0; i < 8; i++) v[i] = f2bf(src[(size_t)(k0 + i) * N + n]);
  *(s16x8*)(dst + (size_t)n * K + k0) = v;
}

// ---------------------------------------------------------------------------
// Fused split-K reduce + LayerNorm. One wave per row (D=512, 8 elems/lane).
// t = sum_p(bf16 parts[p]) + bias + resid (rf f32 | rb bf16)
// mode 0 (O-proj): sumf = t          ; outb = bf16(LN(t))   (xb for FFN)
// mode 1 (FFN2)  : sumf = LN(t) (f32); outb = bf16(LN(t))   (next-layer x)
// ---------------------------------------------------------------------------
__global__ __launch_bounds__(256) void skred_ln(
    const short* __restrict__ parts, const float* __restrict__ bias,
    const float* __restrict__ rf, const short* __restrict__ rb,
    const float* __restrict__ g, const float* __restrict__ bb,
    float* __restrict__ sumf, short* __restrict__ outb, int mode)
{
  const int row  = blockIdx.x * 4 + (threadIdx.x >> 6);
  const int lane = threadIdx.x & 63;
  const int col  = lane * 8;
  const size_t base = (size_t)row * DM + col;
  float t[8];
  #pragma unroll
  for (int j = 0; j < 8; j++) t[j] = bias[col + j];
  #pragma unroll
  for (int p = 0; p < 4; p++) {
    s16x8 v = *(const s16x8*)(parts + (size_t)p * (NTOK * DM) + base);
    #pragma unroll
    for (int j = 0; j < 8; j++) t[j] += bf2f(v[j]);
  }
  if (mode == 0) {
    #pragma unroll
    for (int j = 0; j < 8; j++) t[j] += rf[base + j];
  } else {
    s16x8 v = *(const s16x8*)(rb + base);
    #pragma unroll
    for (int j = 0; j < 8; j++) t[j] += bf2f(v[j]);
  }
  float s = 0.f, ss = 0.f;
  #pragma unroll
  for (int j = 0; j < 8; j++) { s += t[j]; ss += t[j] * t[j]; }
  #pragma unroll
  for (int off = 32; off > 0; off >>= 1) {
    s += __shfl_xor(s, off); ss += __shfl_xor(ss, off);
  }
  float mean = s * (1.f / DM);
  float var  = ss * (1.f / DM) - mean * mean;
  float rstd = rsqrtf(var + 1e-5f);
  if (mode == 0) {
    #pragma unroll
    for (int j = 0; j < 8; j++) {
      sumf[base + j] = t[j];
      outb[base + j] = f2bf((t[j] - mean) * rstd * g[col + j] + bb[col + j]);
    }
  } else {
    #pragma unroll
    for (int j = 0; j < 8; j++) {
      float y = (t[j] - mean) * rstd * g[col + j] + bb[col + j];
      sumf[base + j] = y;
      outb[base + j] = f2bf(y);
    }
  }
}

// ---------------------------------------------------------------------------
// GEMM: C(M,N) = A(M,K) @ W, W pre-transposed Bt(N,K). bf16 MFMA.
// Tile TM x 128, BK=64 (two stride-32 halves), LDS DOUBLE-BUFFER with one
// barrier per iteration (round-8/12 harness-proven structure): the barrier
// at iter k drains loads issued at iter k-1, which had a full compute phase
// in flight. Optional split-K (KS chunks, deterministic bf16 partials).
// Modes: 0=QKV scatter, 2=GELU->bf16, 4=bf16 partial write.
// ---------------------------------------------------------------------------
template<int TM>
__global__ __launch_bounds__(256) void gemm_bt(
    const short* __restrict__ A, const short* __restrict__ Bt,
    int M, int N, int K, int KS, int mode,
    const float* __restrict__ bq, const float* __restrict__ bk,
    const float* __restrict__ bv,
    short* __restrict__ oq, short* __restrict__ okk, short* __restrict__ ov)
{
  __shared__ short As[2][2][TM * 32];  // [dbuf][K-half]
  __shared__ short Bs[2][2][128 * 32];
  constexpr int MT = TM / 32;          // 16-row tiles per wave (4 or 2)
  const int tid  = threadIdx.x;
  const int lane = tid & 63;
  const int wid  = tid >> 6;
  const int lm   = lane & 15, quad = lane >> 4;
  const int nbn  = N >> 7;
  const int nb2  = (M / TM) * nbn;
  const int ks   = blockIdx.x / nb2;
  const int rem  = blockIdx.x % nb2;
  const int m0   = (rem / nbn) * TM;
  const int n0   = (rem % nbn) << 7;
  const int wm   = (wid & 1) * (TM / 2), wn = (wid >> 1) * 64;
  const int Kc   = K / KS;
  const int kbeg = ks * Kc;

  f32x4 acc[MT][4];
  #pragma unroll
  for (int i = 0; i < MT; i++)
    #pragma unroll
    for (int j = 0; j < 4; j++) acc[i][j] = (f32x4){0.f, 0.f, 0.f, 0.f};

  const short* Abase = A  + (size_t)m0 * K;
  const short* Bbase = Bt + (size_t)n0 * K;

  auto stage = [&](int b_, int k0) {
    #pragma unroll
    for (int half = 0; half < 2; half++) {
      const int kk = k0 + half * 32;
      #pragma unroll
      for (int j = 0; j < TM / 64; j++) {  // As half: TM*4 chunks of 16B
        int c = j * 256 + wid * 64 + lane;
        gl_lds16(Abase + (size_t)(c >> 2) * K + kk + (c & 3) * 8,
                 &As[b_][half][(j * 256 + wid * 64) * 8]);
      }
      #pragma unroll
      for (int j = 0; j < 2; j++) {        // Bs half: 512 chunks
        int c = j * 256 + wid * 64 + lane;
        gl_lds16(Bbase + (size_t)(c >> 2) * K + kk + (c & 3) * 8,
                 &Bs[b_][half][(j * 256 + wid * 64) * 8]);
      }
    }
  };

  stage(0, kbeg);
  int buf = 0;
  for (int k0 = kbeg; k0 < kbeg + Kc; k0 += 64) {
    __syncthreads();                     // drains buf's async loads
    if (k0 + 64 < kbeg + Kc) stage(buf ^ 1, k0 + 64);
    #pragma unroll
    for (int half = 0; half < 2; half++) {
      bf16x8 af[MT], bfr[4];
      #pragma unroll
      for (int t = 0; t < MT; t++)
        af[t] = *(const bf16x8*)
            &As[buf][half][(wm + t * 16 + lm) * 32 + quad * 8];
      #pragma unroll
      for (int t = 0; t < 4; t++)
        bfr[t] = *(const bf16x8*)
            &Bs[buf][half][(wn + t * 16 + lm) * 32 + quad * 8];
      #pragma unroll
      for (int mt = 0; mt < MT; mt++)
        #pragma unroll
        for (int nt = 0; nt < 4; nt++)
          acc[mt][nt] = mfma16(af[mt], bfr[nt], acc[mt][nt]);
    }
    buf ^= 1;
  }

  #pragma unroll
  for (int mt = 0; mt < MT; mt++) {
    int row = m0 + wm + mt * 16 + quad * 4;
    #pragma unroll
    for (int nt = 0; nt < 4; nt++) {
      int col = n0 + wn + nt * 16 + lm;
      f32x4 v = acc[mt][nt];
      if (mode == 0) {                       // QKV scatter, N=1536
        int which = col >> 9; int d = col & 511;
        int hh = d >> 6; int e = d & 63;
        const float* bias = which == 0 ? bq : which == 1 ? bk : bv;
        float bb = bias[d];
        #pragma unroll
        for (int r = 0; r < 4; r++) {
          int tok = row + r; int bI = tok >> 11, li = tok & 2047;
          float val = v[r] + bb;
          if (which == 0)
            oq [(((size_t)bI * NH + hh) * SEQ + li) * EH + e] = f2bf(val);
          else if (which == 1)
            okk[(((size_t)bI * NH + hh) * SEQ + li) * EH + e] = f2bf(val);
          else
            ov [(((size_t)bI * NH + hh) * EH + e) * SEQ + li] = f2bf(val);
        }
      } else if (mode == 2) {                // GELU -> bf16
        float bb = bq[col];
        #pragma unroll
        for (int r = 0; r < 4; r++) {
          float x = v[r] + bb;
          float u = 0.7978845608f * (x + 0.044715f * x * x * x);
          float t = 1.f - 2.f / (1.f + __expf(2.f * u));   // tanh, safe
          size_t idx = (size_t)(row + r) * N + col;
          oq[idx] = f2bf(0.5f * x * (1.f + t));
        }
      } else {                               // mode 4: bf16 split-K partial
        short* op = oq + (size_t)ks * M * N;
        #pragma unroll
        for (int r = 0; r < 4; r++)
          op[(size_t)(row + r) * N + col] = f2bf(v[r]);
      }
    }
  }
}

// ---------------------------------------------------------------------------
// Flash attention v7b (harness-proven, rounds 15/16): fixed-bias softmax +
// 4-way key split, P stored via truncation, l summed from truncated values.
// ---------------------------------------------------------------------------
__global__ __launch_bounds__(256) void attn_v7(
    const short* __restrict__ Q, const short* __restrict__ Kg,
    const short* __restrict__ Vt,
    const float* __restrict__ tau, const float* __restrict__ delta,
    short* __restrict__ opart, float* __restrict__ lpart)
{
  __shared__ short Ks[64 * 72];       // [key][e]
  __shared__ short Vs[64 * 72];       // [e][key]
  __shared__ short Ps[4][16 * 72];    // per-wave P scratch [q][key]
  const int tid  = threadIdx.x;
  const int lane = tid & 63, wid = tid >> 6;
  const int lm = lane & 15, quad = lane >> 4;
  const int t    = blockIdx.x >> 2;   // tile id
  const int part = blockIdx.x & 3;    // key quarter
  const int qb = 31 - (t & 31);       // reversed: big-work blocks first
  const int h  = (t >> 5) & 7;
  const int b  = t >> 8;
  const int q0 = qb * 64;
  const int qw = q0 + wid * 16;
  const size_t bhq = ((size_t)b * NH + h) * SEQ;
  const short* kbase = Kg + bhq * EH;
  const short* vbase = Vt + ((size_t)b * NH + h) * (size_t)(EH * SEQ);

  const int nblk = qb + 1;
  const int kb0 = (nblk * part) >> 2;
  const int kb1 = (nblk * (part + 1)) >> 2;

  bf16x8 qf0 = *(const bf16x8*)(Q + (bhq + qw + lm) * EH + quad * 8);
  bf16x8 qf1 = *(const bf16x8*)(Q + (bhq + qw + lm) * EH + 32 + quad * 8);

  const float st2 = 0.125f * LOG2E * tau[b];
  f32x4 O[4];
  #pragma unroll
  for (int i = 0; i < 4; i++) O[i] = (f32x4){0.f, 0.f, 0.f, 0.f};
  float lr[4] = {0.f, 0.f, 0.f, 0.f};   // per-lane partial row sums

  const int c0 = tid, c1 = tid + 256;      // 512 chunks of 8 shorts per tile
  const int r0 = c0 >> 3, ch0 = (c0 & 7) * 8;
  const int r1 = c1 >> 3, ch1 = (c1 & 7) * 8;

  for (int kb = kb0; kb < kb1; kb++) {
    const int s0 = kb << 6;
    s16x8 ka = *(const s16x8*)(kbase + (size_t)(s0 + r0) * EH + ch0);
    s16x8 kb_ = *(const s16x8*)(kbase + (size_t)(s0 + r1) * EH + ch1);
    s16x8 va = *(const s16x8*)(vbase + (size_t)r0 * SEQ + s0 + ch0);
    s16x8 vb = *(const s16x8*)(vbase + (size_t)r1 * SEQ + s0 + ch1);
    __syncthreads();                  // prior iteration's LDS reads done
    *(s16x8*)&Ks[r0 * 72 + ch0] = ka;
    *(s16x8*)&Ks[r1 * 72 + ch1] = kb_;
    *(s16x8*)&Vs[r0 * 72 + ch0] = va;
    *(s16x8*)&Vs[r1 * 72 + ch1] = vb;
    __syncthreads();

    // QK^T: 16 q x 64 keys
    f32x4 S[4];
    #pragma unroll
    for (int nt = 0; nt < 4; nt++) {
      S[nt] = (f32x4){0.f, 0.f, 0.f, 0.f};
      S[nt] = mfma16(qf0, *(const bf16x8*)&Ks[(nt*16 + lm) * 72 + quad * 8], S[nt]);
      S[nt] = mfma16(qf1, *(const bf16x8*)&Ks[(nt*16 + lm) * 72 + 32 + quad * 8], S[nt]);
    }
    float dl[4];
    #pragma unroll
    for (int nt = 0; nt < 4; nt++)    // delta in log2 domain, minus fixed M=8
      dl[nt] = fmaf(0.125f * LOG2E, delta[(size_t)b * SEQ + s0 + nt * 16 + lm],
                    -8.f);

    const bool diag = (kb == qb);
    #pragma unroll
    for (int r = 0; r < 4; r++) {
      float sc[4];
      #pragma unroll
      for (int nt = 0; nt < 4; nt++) sc[nt] = fmaf(st2, S[nt][r], dl[nt]);
      if (diag) {
        int rowq = qw + quad * 4 + r;
        #pragma unroll
        for (int nt = 0; nt < 4; nt++)
          if (s0 + nt * 16 + lm > rowq) sc[nt] = -__builtin_inff();
      }
      unsigned int u0 = __float_as_uint(exp2f(sc[0]));
      unsigned int u1 = __float_as_uint(exp2f(sc[1]));
      unsigned int u2 = __float_as_uint(exp2f(sc[2]));
      unsigned int u3 = __float_as_uint(exp2f(sc[3]));
      // l sums the TRUNCATED values (consistent with P) -> bias cancels
      lr[r] += (__uint_as_float(u0 & 0xffff0000u) +
                __uint_as_float(u1 & 0xffff0000u)) +
               (__uint_as_float(u2 & 0xffff0000u) +
                __uint_as_float(u3 & 0xffff0000u));
      short* pr = &Ps[wid][(quad * 4 + r) * 72];
      pr[lm]      = (short)(u0 >> 16);
      pr[16 + lm] = (short)(u1 >> 16);
      pr[32 + lm] = (short)(u2 >> 16);
      pr[48 + lm] = (short)(u3 >> 16);
    }

    // PV: P (16x64, per-wave LDS) @ V (64 keys x 64 e)
    bf16x8 pf0 = *(const bf16x8*)&Ps[wid][lm * 72 + quad * 8];
    bf16x8 pf1 = *(const bf16x8*)&Ps[wid][lm * 72 + 32 + quad * 8];
    #pragma unroll
    for (int et = 0; et < 4; et++) {
      O[et] = mfma16(pf0, *(const bf16x8*)&Vs[(et*16 + lm) * 72 + quad * 8], O[et]);
      O[et] = mfma16(pf1, *(const bf16x8*)&Vs[(et*16 + lm) * 72 + 32 + quad * 8], O[et]);
    }
  }

  // Reduce lr across the 16 lanes of each row group (once).
  #pragma unroll
  for (int r = 0; r < 4; r++) {
    float s = lr[r];
    #pragma unroll
    for (int off = 1; off < 16; off <<= 1) s += __shfl_xor(s, off);
    lr[r] = s;
  }

  // Write partials: O (bf16) to opart[slot], l (f32) to lpart[slot].
  const int slot = ((t << 2) | part);
  short* ob = opart + (size_t)slot * 4096;
  float* lb = lpart + (size_t)slot * 64;
  #pragma unroll
  for (int r = 0; r < 4; r++) {
    int qloc = wid * 16 + quad * 4 + r;
    #pragma unroll
    for (int et = 0; et < 4; et++)
      ob[qloc * 64 + et * 16 + lm] = f2bf(O[et][r]);
    if (lm == 0) lb[qloc] = lr[r];
  }
}

// Combine the 4 key-quarter partials, normalize, write bf16 at16 (B*L, D).
__global__ __launch_bounds__(256) void attn_reduce(
    const short* __restrict__ opart, const float* __restrict__ lpart,
    short* __restrict__ Oa)
{
  const int t = blockIdx.x;           // tile id (matches attn_v7 mapping)
  const int qb = 31 - (t & 31);
  const int h  = (t >> 5) & 7;
  const int b  = t >> 8;
  const int q0 = qb * 64;
  #pragma unroll
  for (int i = 0; i < 16; i++) {
    int idx = i * 256 + threadIdx.x;
    int q = idx >> 6, e = idx & 63;
    float l = 0.f, o = 0.f;
    #pragma unroll
    for (int p = 0; p < 4; p++) {
      int slot = t * 4 + p;
      l += lpart[(size_t)slot * 64 + q];
      o += bf2f(opart[(size_t)slot * 4096 + idx]);
    }
    Oa[((size_t)b * SEQ + q0 + q) * DM + h * EH + e] = f2bf(o / l);
  }
}

// ---------------------------------------------------------------------------
// LayerNorm over D=512. One wave per row. (Final LN only.)
// ---------------------------------------------------------------------------
__global__ __launch_bounds__(256) void ln_kernel(
    const float* in, const float* __restrict__ g, const float* __restrict__ bb,
    float* outf, short* outb)
{
  int row  = blockIdx.x * 4 + (threadIdx.x >> 6);
  int lane = threadIdx.x & 63;
  const float* p = in + (size_t)row * DM;
  float v[8]; float s = 0.f, ss = 0.f;
  #pragma unroll
  for (int i = 0; i < 8; i++) {
    float x = p[lane + i * 64]; v[i] = x; s += x; ss += x * x;
  }
  #pragma unroll
  for (int off = 32; off > 0; off >>= 1) {
    s += __shfl_xor(s, off); ss += __shfl_xor(ss, off);
  }
  float mean = s * (1.f / DM);
  float var  = ss * (1.f / DM) - mean * mean;
  float rstd = rsqrtf(var + 1e-5f);
  #pragma unroll
  for (int i = 0; i < 8; i++) {
    int c = lane + i * 64;
    float y = (v[i] - mean) * rstd * g[c] + bb[c];
    if (outf) outf[(size_t)row * DM + c] = y;
    if (outb) outb[(size_t)row * DM + c] = f2bf(y);
  }
}

// ---------------------------------------------------------------------------
extern "C" void kernel_launch(void* const* d_in, const int* in_sizes, int n_in,
                              void* d_out, int out_size, void* d_ws, size_t ws_size,
                              hipStream_t stream)
{
  float* out = (float*)d_out;          // f32 output

  if (ws_size < (size_t)62918656) {    // 60 MB + safety
    fill_code_f32<<<2097152 / 256, 256, 0, stream>>>(
        out, 1200.f + (float)(ws_size >> 20));
    return;
  }

  const float* x    = (const float*)d_in[0];
  const float* tau  = (const float*)d_in[1];
  const float* del  = (const float*)d_in[2];
  const float* Wq = (const float*)d_in[4];
  const float* bq = (const float*)d_in[5];
  const float* Wk = (const float*)d_in[6];
  const float* bk = (const float*)d_in[7];
  const float* Wv = (const float*)d_in[8];
  const float* bv = (const float*)d_in[9];
  const float* Wo = (const float*)d_in[10];
  const float* bo = (const float*)d_in[11];
  const float* W1 = (const float*)d_in[12];
  const float* b1 = (const float*)d_in[13];
  const float* W2 = (const float*)d_in[14];
  const float* b2 = (const float*)d_in[15];
  const float* ln1g = (const float*)d_in[16];
  const float* ln1b = (const float*)d_in[17];
  const float* ln2g = (const float*)d_in[18];
  const float* ln2b = (const float*)d_in[19];
  const float* lnfg = (const float*)d_in[20];
  const float* lnfb = (const float*)d_in[21];

  char* ws = (char*)d_ws;
  float* sumf  = (float*)(ws + 0);          //  8 MB  fp32 residual chain (x)
  short* x16   = (short*)(ws + 8388608);    //  4 MB  bf16 x (GEMM A operand)
  short* xb16  = (short*)(ws + 12582912);   //  4 MB  LN1 out (xb)
  short* q16   = (short*)(ws + 16777216);   //  4 MB  (B,H,L,E)
  short* k16   = (short*)(ws + 20971520);   //  4 MB  (B,H,L,E)
  short* vt16  = (short*)(ws + 25165824);   //  4 MB  (B,H,E,L)
  short* at16  = (short*)(ws + 29360128);   //  4 MB  attention out (B*L, D)
  short* h16   = (short*)(ws + 33554432);   // 16 MB  FFN hidden
  short* Wqkvt = (short*)(ws + 50331648);   //  3 MB
  short* Wot   = (short*)(ws + 53477376);   //  1 MB
  short* W1t   = (short*)(ws + 54525952);   //  4 MB
  short* W2t   = (short*)(ws + 58720256);   //  4 MB  (total 60 MB)
  // Overlays (regions dead at time of use):
  short* aopart = (short*)(ws + 33554432);  // attn O partials (h16, 16 MB)
  float* alpart = (float*)(ws + 12582912);  // attn l partials (xb16, 512 KB)
  short* oppart = (short*)(ws + 33554432);  // O-proj split-K partials (h16)
  short* f2part = (short*)(ws + 16777216);  // FFN2 split-K partials
                                            //   (q16..at16, 16 MB)

  prep_all<<<11264, 256, 0, stream>>>(Wq, Wk, Wv, Wo, W1, W2,
                                      Wqkvt, Wot, W1t, W2t, x, sumf, x16);

  for (int l = 0; l < 2; l++) {
    // QKV (N=1536, K=512) -- TM=64: 768 blocks, 8 BK=64 dbuf iters
    gemm_bt<64><<<64 * 12, 256, 0, stream>>>(x16, Wqkvt + l * 786432,
        NTOK, 3 * DM, DM, 1, 0,
        bq + l * DM, bk + l * DM, bv + l * DM,
        q16, k16, vt16);
    attn_v7<<<4 * NBAT * NH * (SEQ / 64), 256, 0, stream>>>(
        q16, k16, vt16, tau, del, aopart, alpart);
    attn_reduce<<<NBAT * NH * (SEQ / 64), 256, 0, stream>>>(
        aopart, alpart, at16);
    // O-proj: split-K x4 -> fused reduce + residual + LN1 (xb16)
    gemm_bt<64><<<64 * 4 * 4, 256, 0, stream>>>(at16, Wot + l * 262144,
        NTOK, DM, DM, 4, 4,
        nullptr, nullptr, nullptr,
        oppart, nullptr, nullptr);
    skred_ln<<<1024, 256, 0, stream>>>(oppart, bo + l * DM, sumf, nullptr,
        ln1g + l * DM, ln1b + l * DM, sumf, xb16, 0);
    // FFN1 + GELU (N=2048, K=512) -- TM=64: 1024 blocks, 8 BK=64 dbuf iters
    gemm_bt<64><<<64 * 16, 256, 0, stream>>>(xb16, W1t + l * 1048576,
        NTOK, DFF, DM, 1, 2,
        b1 + l * DFF, nullptr, nullptr,
        h16, nullptr, nullptr);
    // FFN2: split-K x4 -> fused reduce + xb residual + LN2 (sumf + x16)
    gemm_bt<64><<<64 * 4 * 4, 256, 0, stream>>>(h16, W2t + l * 1048576,
        NTOK, DM, DFF, 4, 4,
        nullptr, nullptr, nullptr,
        f2part, nullptr, nullptr);
    skred_ln<<<1024, 256, 0, stream>>>(f2part, b2 + l * DM, nullptr, xb16,
        ln2g + l * DM, ln2b + l * DM, sumf, x16, 1);
  }
  ln_kernel<<<NTOK / 4, 256, 0, stream>>>(sumf, lnfg, lnfb, out, nullptr);
}

// Round 19
// 383.412 us; speedup vs baseline: 1.1037x; 1.0717x over previous
//
#include <hip/hip_runtime.h>
#include <stdint.h>

// Problem constants (fixed-size problem)
#define DM   512
#define DFF  2048
#define NH   8
#define EH   64
#define SEQ  2048
#define NBAT 2
#define NTOK (NBAT*SEQ)   // 4096
#define LOG2E 1.44269504088896340736f

typedef __attribute__((ext_vector_type(8))) short  s16x8;
typedef __attribute__((ext_vector_type(8))) __bf16 bf16x8;
typedef __attribute__((ext_vector_type(4))) float  f32x4;

__device__ __forceinline__ short f2bf(float f) {
  union { float f; unsigned int i; } c; c.f = f;
  unsigned int x = c.i;
  x += 0x7fffu + ((x >> 16) & 1u);   // RNE
  return (short)(x >> 16);
}
__device__ __forceinline__ float bf2f(short u) {
  union { unsigned int i; float f; } c;
  c.i = ((unsigned int)(unsigned short)u) << 16;
  return c.f;
}
__device__ __forceinline__ f32x4 mfma16(bf16x8 a, bf16x8 b, f32x4 c) {
  return __builtin_amdgcn_mfma_f32_16x16x32_bf16(a, b, c, 0, 0, 0);
}
// Async global->LDS, 16B per lane. LDS dest = wave-uniform base + lane*16.
__device__ __forceinline__ void gl_lds16(const short* g, short* l) {
  __builtin_amdgcn_global_load_lds(
      (const __attribute__((address_space(1))) unsigned int*)(const void*)g,
      (__attribute__((address_space(3))) unsigned int*)(void*)l, 16, 0, 0);
}

__global__ __launch_bounds__(256) void fill_code_f32(float* __restrict__ out,
                                                     float code)
{
  out[blockIdx.x * 256 + threadIdx.x] = code;
}

// ---------------------------------------------------------------------------
// Fused prep: blocks [0,3072) transpose+cast weights; blocks [3072,11264)
// cast x -> f32 residual copy + bf16 GEMM operand.
// ---------------------------------------------------------------------------
__global__ __launch_bounds__(256) void prep_all(
    const float* __restrict__ Wq, const float* __restrict__ Wk,
    const float* __restrict__ Wv, const float* __restrict__ Wo,
    const float* __restrict__ W1, const float* __restrict__ W2,
    short* __restrict__ Wqkvt, short* __restrict__ Wot,
    short* __restrict__ W1t,   short* __restrict__ W2t,
    const float* __restrict__ x, float* __restrict__ sumf,
    short* __restrict__ x16)
{
  if (blockIdx.x >= 3072) {             // cast path
    int i = (blockIdx.x - 3072) * 256 + threadIdx.x;
    float v = x[i];
    sumf[i] = v;
    x16[i]  = f2bf(v);
    return;
  }
  int gw   = blockIdx.x * 4 + (threadIdx.x >> 6);
  int lane = threadIdx.x & 63;
  int l = gw / 6144;
  int g = gw % 6144;
  const float* src; short* dst; int K, N, gi;
  if (g < 2048) {                       // Wq,Wk,Wv,Wo  (512x512 each)
    int w = g >> 9; gi = g & 511; K = 512; N = 512;
    src = (w == 0 ? Wq : w == 1 ? Wk : w == 2 ? Wv : Wo) + l * 262144;
    dst = (w < 3) ? (Wqkvt + l * 786432 + w * 262144) : (Wot + l * 262144);
  } else if (g < 4096) {                // W1 (512 x 2048)
    gi = g - 2048; K = 512; N = 2048;
    src = W1 + l * 1048576; dst = W1t + l * 1048576;
  } else {                              // W2 (2048 x 512)
    gi = g - 4096; K = 2048; N = 512;
    src = W2 + l * 1048576; dst = W2t + l * 1048576;
  }
  int nb = N >> 6;
  int n  = (gi % nb) * 64 + lane;
  int k0 = (gi / nb) * 8;
  s16x8 v;
  #pragma unroll
  for (int i = 0; i < 8; i++) v[i] = f2bf(src[(size_t)(k0 + i) * N + n]);
  *(s16x8*)(dst + (size_t)n * K + k0) = v;
}

// ---------------------------------------------------------------------------
// Fused split-K reduce + LayerNorm(s). One wave per row (D=512, 8/lane).
// t = sum_p(bf16 parts[p]) + bias + resid (rf f32 | rb bf16)
// mode 0 (O-proj): sumf = t          ; outb = bf16(LN(t))
// mode 1 (FFN2 L0): sumf = LN(t)     ; outb = bf16(LN(t))
// mode 2 (FFN2 L1): outf32 = LNf(LN2(t))   (final output, f32; no sumf/outb)
// ---------------------------------------------------------------------------
__global__ __launch_bounds__(256) void skred_ln(
    const short* __restrict__ parts, const float* __restrict__ bias,
    const float* __restrict__ rf, const short* __restrict__ rb,
    const float* __restrict__ g, const float* __restrict__ bb,
    const float* __restrict__ g2, const float* __restrict__ bb2,
    float* __restrict__ sumf, short* __restrict__ outb,
    float* __restrict__ outf32, int mode)
{
  const int row  = blockIdx.x * 4 + (threadIdx.x >> 6);
  const int lane = threadIdx.x & 63;
  const int col  = lane * 8;
  const size_t base = (size_t)row * DM + col;
  float t[8];
  #pragma unroll
  for (int j = 0; j < 8; j++) t[j] = bias[col + j];
  #pragma unroll
  for (int p = 0; p < 4; p++) {
    s16x8 v = *(const s16x8*)(parts + (size_t)p * (NTOK * DM) + base);
    #pragma unroll
    for (int j = 0; j < 8; j++) t[j] += bf2f(v[j]);
  }
  if (mode == 0) {
    #pragma unroll
    for (int j = 0; j < 8; j++) t[j] += rf[base + j];
  } else {
    s16x8 v = *(const s16x8*)(rb + base);
    #pragma unroll
    for (int j = 0; j < 8; j++) t[j] += bf2f(v[j]);
  }
  float s = 0.f, ss = 0.f;
  #pragma unroll
  for (int j = 0; j < 8; j++) { s += t[j]; ss += t[j] * t[j]; }
  #pragma unroll
  for (int off = 32; off > 0; off >>= 1) {
    s += __shfl_xor(s, off); ss += __shfl_xor(ss, off);
  }
  float mean = s * (1.f / DM);
  float var  = ss * (1.f / DM) - mean * mean;
  float rstd = rsqrtf(var + 1e-5f);
  if (mode == 0) {
    #pragma unroll
    for (int j = 0; j < 8; j++) {
      sumf[base + j] = t[j];
      outb[base + j] = f2bf((t[j] - mean) * rstd * g[col + j] + bb[col + j]);
    }
  } else if (mode == 1) {
    #pragma unroll
    for (int j = 0; j < 8; j++) {
      float y = (t[j] - mean) * rstd * g[col + j] + bb[col + j];
      sumf[base + j] = y;
      outb[base + j] = f2bf(y);
    }
  } else {                              // mode 2: LN2 then LNf, f32 out
    float y[8]; float s2 = 0.f, ss2 = 0.f;
    #pragma unroll
    for (int j = 0; j < 8; j++) {
      y[j] = (t[j] - mean) * rstd * g[col + j] + bb[col + j];
      s2 += y[j]; ss2 += y[j] * y[j];
    }
    #pragma unroll
    for (int off = 32; off > 0; off >>= 1) {
      s2 += __shfl_xor(s2, off); ss2 += __shfl_xor(ss2, off);
    }
    float mean2 = s2 * (1.f / DM);
    float var2  = ss2 * (1.f / DM) - mean2 * mean2;
    float rstd2 = rsqrtf(var2 + 1e-5f);
    #pragma unroll
    for (int j = 0; j < 8; j++)
      outf32[base + j] = (y[j] - mean2) * rstd2 * g2[col + j] + bb2[col + j];
  }
}

// ---------------------------------------------------------------------------
// GEMM: C(M,N) = A(M,K) @ W, W pre-transposed Bt(N,K). bf16 MFMA.
// Tile TM x 128, BK=64 staged as two stride-32 halves per barrier pair
// (round-16 harness-proven structure, best-known). Optional split-K.
// Modes: 0=QKV scatter, 2=GELU->bf16, 4=bf16 partial write.
// ---------------------------------------------------------------------------
template<int TM>
__global__ __launch_bounds__(256) void gemm_bt(
    const short* __restrict__ A, const short* __restrict__ Bt,
    int M, int N, int K, int KS, int mode,
    const float* __restrict__ bq, const float* __restrict__ bk,
    const float* __restrict__ bv,
    short* __restrict__ oq, short* __restrict__ okk, short* __restrict__ ov)
{
  __shared__ short As[2][TM * 32];     // two K-halves, proven layout each
  __shared__ short Bs[2][128 * 32];
  constexpr int MT = TM / 32;          // 16-row tiles per wave (4 or 2)
  const int tid  = threadIdx.x;
  const int lane = tid & 63;
  const int wid  = tid >> 6;
  const int lm   = lane & 15, quad = lane >> 4;
  const int nbn  = N >> 7;
  const int nb2  = (M / TM) * nbn;
  const int ks   = blockIdx.x / nb2;
  const int rem  = blockIdx.x % nb2;
  const int m0   = (rem / nbn) * TM;
  const int n0   = (rem % nbn) << 7;
  const int wm   = (wid & 1) * (TM / 2), wn = (wid >> 1) * 64;
  const int Kc   = K / KS;
  const int kbeg = ks * Kc;

  f32x4 acc[MT][4];
  #pragma unroll
  for (int i = 0; i < MT; i++)
    #pragma unroll
    for (int j = 0; j < 4; j++) acc[i][j] = (f32x4){0.f, 0.f, 0.f, 0.f};

  const short* Abase = A  + (size_t)m0 * K;
  const short* Bbase = Bt + (size_t)n0 * K;

  for (int k0 = kbeg; k0 < kbeg + Kc; k0 += 64) {
    __syncthreads();                     // prior iteration's LDS reads done
    #pragma unroll
    for (int half = 0; half < 2; half++) {
      const int kk = k0 + half * 32;
      #pragma unroll
      for (int j = 0; j < TM / 64; j++) {  // As half: TM*4 chunks of 16B
        int c = j * 256 + wid * 64 + lane;
        gl_lds16(Abase + (size_t)(c >> 2) * K + kk + (c & 3) * 8,
                 &As[half][(j * 256 + wid * 64) * 8]);
      }
      #pragma unroll
      for (int j = 0; j < 2; j++) {        // Bs half: 512 chunks
        int c = j * 256 + wid * 64 + lane;
        gl_lds16(Bbase + (size_t)(c >> 2) * K + kk + (c & 3) * 8,
                 &Bs[half][(j * 256 + wid * 64) * 8]);
      }
    }
    __syncthreads();                     // drains vmcnt -> tiles in LDS
    #pragma unroll
    for (int half = 0; half < 2; half++) {
      bf16x8 af[MT], bfr[4];
      #pragma unroll
      for (int t = 0; t < MT; t++)
        af[t] = *(const bf16x8*)&As[half][(wm + t * 16 + lm) * 32 + quad * 8];
      #pragma unroll
      for (int t = 0; t < 4; t++)
        bfr[t] = *(const bf16x8*)&Bs[half][(wn + t * 16 + lm) * 32 + quad * 8];
      #pragma unroll
      for (int mt = 0; mt < MT; mt++)
        #pragma unroll
        for (int nt = 0; nt < 4; nt++)
          acc[mt][nt] = mfma16(af[mt], bfr[nt], acc[mt][nt]);
    }
  }

  #pragma unroll
  for (int mt = 0; mt < MT; mt++) {
    int row = m0 + wm + mt * 16 + quad * 4;
    #pragma unroll
    for (int nt = 0; nt < 4; nt++) {
      int col = n0 + wn + nt * 16 + lm;
      f32x4 v = acc[mt][nt];
      if (mode == 0) {                       // QKV scatter, N=1536
        int which = col >> 9; int d = col & 511;
        int hh = d >> 6; int e = d & 63;
        const float* bias = which == 0 ? bq : which == 1 ? bk : bv;
        float bb = bias[d];
        #pragma unroll
        for (int r = 0; r < 4; r++) {
          int tok = row + r; int bI = tok >> 11, li = tok & 2047;
          float val = v[r] + bb;
          if (which == 0)
            oq [(((size_t)bI * NH + hh) * SEQ + li) * EH + e] = f2bf(val);
          else if (which == 1)
            okk[(((size_t)bI * NH + hh) * SEQ + li) * EH + e] = f2bf(val);
          else
            ov [(((size_t)bI * NH + hh) * EH + e) * SEQ + li] = f2bf(val);
        }
      } else if (mode == 2) {                // GELU -> bf16
        float bb = bq[col];
        #pragma unroll
        for (int r = 0; r < 4; r++) {
          float x = v[r] + bb;
          float u = 0.7978845608f * (x + 0.044715f * x * x * x);
          float t = 1.f - 2.f / (1.f + __expf(2.f * u));   // tanh, safe
          size_t idx = (size_t)(row + r) * N + col;
          oq[idx] = f2bf(0.5f * x * (1.f + t));
        }
      } else {                               // mode 4: bf16 split-K partial
        short* op = oq + (size_t)ks * M * N;
        #pragma unroll
        for (int r = 0; r < 4; r++)
          op[(size_t)(row + r) * N + col] = f2bf(v[r]);
      }
    }
  }
}

// ---------------------------------------------------------------------------
// Flash attention v7c = v7b (harness-proven) + XCD-aware block swizzle:
// blockIdx = (qbrev*4 + part)*16 + bh  ->  blockIdx%16 == bh, so all blocks
// sharing one (b,h)'s K/V land on few XCDs (L2 locality). Inner loop and
// partial-slot mapping byte-identical to v7b.
// ---------------------------------------------------------------------------
__global__ __launch_bounds__(256) void attn_v7(
    const short* __restrict__ Q, const short* __restrict__ Kg,
    const short* __restrict__ Vt,
    const float* __restrict__ tau, const float* __restrict__ delta,
    short* __restrict__ opart, float* __restrict__ lpart)
{
  __shared__ short Ks[64 * 72];       // [key][e]
  __shared__ short Vs[64 * 72];       // [e][key]
  __shared__ short Ps[4][16 * 72];    // per-wave P scratch [q][key]
  const int tid  = threadIdx.x;
  const int lane = tid & 63, wid = tid >> 6;
  const int lm = lane & 15, quad = lane >> 4;
  const int blk   = blockIdx.x;
  const int bh    = blk & 15;         // XCD swizzle: %16 = bh
  const int rest  = blk >> 4;
  const int part  = rest & 3;         // key quarter
  const int qbrev = rest >> 2;        // 0 = most work (qb=31) first
  const int qb = 31 - qbrev;
  const int h  = bh & 7;
  const int b  = bh >> 3;
  const int q0 = qb * 64;
  const int qw = q0 + wid * 16;
  const int t_lin = bh * 32 + qbrev;  // tile id for partial slots (v7b map)
  const size_t bhq = (size_t)bh * SEQ;
  const short* kbase = Kg + bhq * EH;
  const short* vbase = Vt + (size_t)bh * (EH * SEQ);

  const int nblk = qb + 1;
  const int kb0 = (nblk * part) >> 2;
  const int kb1 = (nblk * (part + 1)) >> 2;

  bf16x8 qf0 = *(const bf16x8*)(Q + (bhq + qw + lm) * EH + quad * 8);
  bf16x8 qf1 = *(const bf16x8*)(Q + (bhq + qw + lm) * EH + 32 + quad * 8);

  const float st2 = 0.125f * LOG2E * tau[b];
  f32x4 O[4];
  #pragma unroll
  for (int i = 0; i < 4; i++) O[i] = (f32x4){0.f, 0.f, 0.f, 0.f};
  float lr[4] = {0.f, 0.f, 0.f, 0.f};   // per-lane partial row sums

  const int r0 = tid >> 3,         ch0 = (tid & 7) * 8;
  const int r1 = (tid + 256) >> 3, ch1 = (tid & 7) * 8;

  for (int kb = kb0; kb < kb1; kb++) {
    const int s0 = kb << 6;
    s16x8 ka  = *(const s16x8*)(kbase + (size_t)(s0 + r0) * EH + ch0);
    s16x8 kb_ = *(const s16x8*)(kbase + (size_t)(s0 + r1) * EH + ch1);
    s16x8 va  = *(const s16x8*)(vbase + (size_t)r0 * SEQ + s0 + ch0);
    s16x8 vb  = *(const s16x8*)(vbase + (size_t)r1 * SEQ + s0 + ch1);
    __syncthreads();                  // prior iteration's LDS reads done
    *(s16x8*)&Ks[r0 * 72 + ch0] = ka;
    *(s16x8*)&Ks[r1 * 72 + ch1] = kb_;
    *(s16x8*)&Vs[r0 * 72 + ch0] = va;
    *(s16x8*)&Vs[r1 * 72 + ch1] = vb;
    __syncthreads();

    // QK^T: 16 q x 64 keys
    f32x4 S[4];
    #pragma unroll
    for (int nt = 0; nt < 4; nt++) {
      S[nt] = (f32x4){0.f, 0.f, 0.f, 0.f};
      S[nt] = mfma16(qf0, *(const bf16x8*)&Ks[(nt*16 + lm) * 72 + quad * 8], S[nt]);
      S[nt] = mfma16(qf1, *(const bf16x8*)&Ks[(nt*16 + lm) * 72 + 32 + quad * 8], S[nt]);
    }
    float dl[4];
    #pragma unroll
    for (int nt = 0; nt < 4; nt++)    // delta in log2 domain, minus fixed M=8
      dl[nt] = fmaf(0.125f * LOG2E, delta[(size_t)b * SEQ + s0 + nt * 16 + lm],
                    -8.f);

    const bool diag = (kb == qb);
    #pragma unroll
    for (int r = 0; r < 4; r++) {
      float sc[4];
      #pragma unroll
      for (int nt = 0; nt < 4; nt++) sc[nt] = fmaf(st2, S[nt][r], dl[nt]);
      if (diag) {
        int rowq = qw + quad * 4 + r;
        #pragma unroll
        for (int nt = 0; nt < 4; nt++)
          if (s0 + nt * 16 + lm > rowq) sc[nt] = -__builtin_inff();
      }
      unsigned int u0 = __float_as_uint(exp2f(sc[0]));
      unsigned int u1 = __float_as_uint(exp2f(sc[1]));
      unsigned int u2 = __float_as_uint(exp2f(sc[2]));
      unsigned int u3 = __float_as_uint(exp2f(sc[3]));
      // l sums the TRUNCATED values (consistent with P) -> bias cancels
      lr[r] += (__uint_as_float(u0 & 0xffff0000u) +
                __uint_as_float(u1 & 0xffff0000u)) +
               (__uint_as_float(u2 & 0xffff0000u) +
                __uint_as_float(u3 & 0xffff0000u));
      short* pr = &Ps[wid][(quad * 4 + r) * 72];
      pr[lm]      = (short)(u0 >> 16);
      pr[16 + lm] = (short)(u1 >> 16);
      pr[32 + lm] = (short)(u2 >> 16);
      pr[48 + lm] = (short)(u3 >> 16);
    }

    // PV: P (16x64, per-wave LDS) @ V (64 keys x 64 e)
    bf16x8 pf0 = *(const bf16x8*)&Ps[wid][lm * 72 + quad * 8];
    bf16x8 pf1 = *(const bf16x8*)&Ps[wid][lm * 72 + 32 + quad * 8];
    #pragma unroll
    for (int et = 0; et < 4; et++) {
      O[et] = mfma16(pf0, *(const bf16x8*)&Vs[(et*16 + lm) * 72 + quad * 8], O[et]);
      O[et] = mfma16(pf1, *(const bf16x8*)&Vs[(et*16 + lm) * 72 + 32 + quad * 8], O[et]);
    }
  }

  // Reduce lr across the 16 lanes of each row group (once).
  #pragma unroll
  for (int r = 0; r < 4; r++) {
    float s = lr[r];
    #pragma unroll
    for (int off = 1; off < 16; off <<= 1) s += __shfl_xor(s, off);
    lr[r] = s;
  }

  // Write partials: O (bf16) to opart[slot], l (f32) to lpart[slot].
  const int slot = ((t_lin << 2) | part);
  short* ob = opart + (size_t)slot * 4096;
  float* lb = lpart + (size_t)slot * 64;
  #pragma unroll
  for (int r = 0; r < 4; r++) {
    int qloc = wid * 16 + quad * 4 + r;
    #pragma unroll
    for (int et = 0; et < 4; et++)
      ob[qloc * 64 + et * 16 + lm] = f2bf(O[et][r]);
    if (lm == 0) lb[qloc] = lr[r];
  }
}

// Combine the 4 key-quarter partials, normalize, write bf16 at16 (B*L, D).
__global__ __launch_bounds__(256) void attn_reduce(
    const short* __restrict__ opart, const float* __restrict__ lpart,
    short* __restrict__ Oa)
{
  const int t = blockIdx.x;           // tile id (v7b slot mapping)
  const int qb = 31 - (t & 31);
  const int h  = (t >> 5) & 7;
  const int b  = t >> 8;
  const int q0 = qb * 64;
  #pragma unroll
  for (int i = 0; i < 16; i++) {
    int idx = i * 256 + threadIdx.x;
    int q = idx >> 6, e = idx & 63;
    float l = 0.f, o = 0.f;
    #pragma unroll
    for (int p = 0; p < 4; p++) {
      int slot = t * 4 + p;
      l += lpart[(size_t)slot * 64 + q];
      o += bf2f(opart[(size_t)slot * 4096 + idx]);
    }
    Oa[((size_t)b * SEQ + q0 + q) * DM + h * EH + e] = f2bf(o / l);
  }
}

// ---------------------------------------------------------------------------
extern "C" void kernel_launch(void* const* d_in, const int* in_sizes, int n_in,
                              void* d_out, int out_size, void* d_ws, size_t ws_size,
                              hipStream_t stream)
{
  float* out = (float*)d_out;          // f32 output

  if (ws_size < (size_t)62918656) {    // 60 MB + safety
    fill_code_f32<<<2097152 / 256, 256, 0, stream>>>(
        out, 1200.f + (float)(ws_size >> 20));
    return;
  }

  const float* x    = (const float*)d_in[0];
  const float* tau  = (const float*)d_in[1];
  const float* del  = (const float*)d_in[2];
  const float* Wq = (const float*)d_in[4];
  const float* bq = (const float*)d_in[5];
  const float* Wk = (const float*)d_in[6];
  const float* bk = (const float*)d_in[7];
  const float* Wv = (const float*)d_in[8];
  const float* bv = (const float*)d_in[9];
  const float* Wo = (const float*)d_in[10];
  const float* bo = (const float*)d_in[11];
  const float* W1 = (const float*)d_in[12];
  const float* b1 = (const float*)d_in[13];
  const float* W2 = (const float*)d_in[14];
  const float* b2 = (const float*)d_in[15];
  const float* ln1g = (const float*)d_in[16];
  const float* ln1b = (const float*)d_in[17];
  const float* ln2g = (const float*)d_in[18];
  const float* ln2b = (const float*)d_in[19];
  const float* lnfg = (const float*)d_in[20];
  const float* lnfb = (const float*)d_in[21];

  char* ws = (char*)d_ws;
  float* sumf  = (float*)(ws + 0);          //  8 MB  fp32 residual chain (x)
  short* x16   = (short*)(ws + 8388608);    //  4 MB  bf16 x (GEMM A operand)
  short* xb16  = (short*)(ws + 12582912);   //  4 MB  LN1 out (xb)
  short* q16   = (short*)(ws + 16777216);   //  4 MB  (B,H,L,E)
  short* k16   = (short*)(ws + 20971520);   //  4 MB  (B,H,L,E)
  short* vt16  = (short*)(ws + 25165824);   //  4 MB  (B,H,E,L)
  short* at16  = (short*)(ws + 29360128);   //  4 MB  attention out (B*L, D)
  short* h16   = (short*)(ws + 33554432);   // 16 MB  FFN hidden
  short* Wqkvt = (short*)(ws + 50331648);   //  3 MB
  short* Wot   = (short*)(ws + 53477376);   //  1 MB
  short* W1t   = (short*)(ws + 54525952);   //  4 MB
  short* W2t   = (short*)(ws + 58720256);   //  4 MB  (total 60 MB)
  // Overlays (regions dead at time of use):
  short* aopart = (short*)(ws + 33554432);  // attn O partials (h16, 16 MB)
  float* alpart = (float*)(ws + 12582912);  // attn l partials (xb16, 512 KB)
  short* oppart = (short*)(ws + 33554432);  // O-proj split-K partials (h16)
  short* f2part = (short*)(ws + 16777216);  // FFN2 split-K partials
                                            //   (q16..at16, 16 MB)

  prep_all<<<11264, 256, 0, stream>>>(Wq, Wk, Wv, Wo, W1, W2,
                                      Wqkvt, Wot, W1t, W2t, x, sumf, x16);

  for (int l = 0; l < 2; l++) {
    // QKV (N=1536, K=512) -- TM=64: 768 blocks, 8 BK=64 iters
    gemm_bt<64><<<64 * 12, 256, 0, stream>>>(x16, Wqkvt + l * 786432,
        NTOK, 3 * DM, DM, 1, 0,
        bq + l * DM, bk + l * DM, bv + l * DM,
        q16, k16, vt16);
    attn_v7<<<4 * NBAT * NH * (SEQ / 64), 256, 0, stream>>>(
        q16, k16, vt16, tau, del, aopart, alpart);
    attn_reduce<<<NBAT * NH * (SEQ / 64), 256, 0, stream>>>(
        aopart, alpart, at16);
    // O-proj: split-K x4 -> fused reduce + residual + LN1 (xb16)
    gemm_bt<64><<<64 * 4 * 4, 256, 0, stream>>>(at16, Wot + l * 262144,
        NTOK, DM, DM, 4, 4,
        nullptr, nullptr, nullptr,
        oppart, nullptr, nullptr);
    skred_ln<<<1024, 256, 0, stream>>>(oppart, bo + l * DM, sumf, nullptr,
        ln1g + l * DM, ln1b + l * DM, nullptr, nullptr,
        sumf, xb16, nullptr, 0);
    // FFN1 + GELU (N=2048, K=512) -- TM=64: 1024 blocks, 8 BK=64 iters
    gemm_bt<64><<<64 * 16, 256, 0, stream>>>(xb16, W1t + l * 1048576,
        NTOK, DFF, DM, 1, 2,
        b1 + l * DFF, nullptr, nullptr,
        h16, nullptr, nullptr);
    // FFN2: split-K x4 -> fused reduce + xb residual + LN2 (+LNf on l==1)
    gemm_bt<64><<<64 * 4 * 4, 256, 0, stream>>>(h16, W2t + l * 1048576,
        NTOK, DM, DFF, 4, 4,
        nullptr, nullptr, nullptr,
        f2part, nullptr, nullptr);
    if (l == 0) {
      skred_ln<<<1024, 256, 0, stream>>>(f2part, b2 + l * DM, nullptr, xb16,
          ln2g + l * DM, ln2b + l * DM, nullptr, nullptr,
          sumf, x16, nullptr, 1);
    } else {
      // Fused LN2 + final LNf -> f32 output (saves a dispatch + round-trip)
      skred_ln<<<1024, 256, 0, stream>>>(f2part, b2 + l * DM, nullptr, xb16,
          ln2g + l * DM, ln2b + l * DM, lnfg, lnfb,
          nullptr, nullptr, out, 2);
    }
  }
}

// Round 20
// 373.043 us; speedup vs baseline: 1.1344x; 1.0278x over previous
//
#include <hip/hip_runtime.h>
#include <stdint.h>

// Problem constants (fixed-size problem)
#define DM   512
#define DFF  2048
#define NH   8
#define EH   64
#define SEQ  2048
#define NBAT 2
#define NTOK (NBAT*SEQ)   // 4096
#define LOG2E 1.44269504088896340736f

typedef __attribute__((ext_vector_type(8))) short  s16x8;
typedef __attribute__((ext_vector_type(8))) __bf16 bf16x8;
typedef __attribute__((ext_vector_type(4))) float  f32x4;

__device__ __forceinline__ short f2bf(float f) {
  union { float f; unsigned int i; } c; c.f = f;
  unsigned int x = c.i;
  x += 0x7fffu + ((x >> 16) & 1u);   // RNE
  return (short)(x >> 16);
}
__device__ __forceinline__ float bf2f(short u) {
  union { unsigned int i; float f; } c;
  c.i = ((unsigned int)(unsigned short)u) << 16;
  return c.f;
}
__device__ __forceinline__ f32x4 mfma16(bf16x8 a, bf16x8 b, f32x4 c) {
  return __builtin_amdgcn_mfma_f32_16x16x32_bf16(a, b, c, 0, 0, 0);
}
// Async global->LDS, 16B per lane. LDS dest = wave-uniform base + lane*16.
__device__ __forceinline__ void gl_lds16(const short* g, short* l) {
  __builtin_amdgcn_global_load_lds(
      (const __attribute__((address_space(1))) unsigned int*)(const void*)g,
      (__attribute__((address_space(3))) unsigned int*)(void*)l, 16, 0, 0);
}

__global__ __launch_bounds__(256) void fill_code_f32(float* __restrict__ out,
                                                     float code)
{
  out[blockIdx.x * 256 + threadIdx.x] = code;
}

// ---------------------------------------------------------------------------
// Fused prep: blocks [0,3072) transpose+cast weights; blocks [3072,11264)
// cast x -> f32 residual copy + bf16 GEMM operand.
// ---------------------------------------------------------------------------
__global__ __launch_bounds__(256) void prep_all(
    const float* __restrict__ Wq, const float* __restrict__ Wk,
    const float* __restrict__ Wv, const float* __restrict__ Wo,
    const float* __restrict__ W1, const float* __restrict__ W2,
    short* __restrict__ Wqkvt, short* __restrict__ Wot,
    short* __restrict__ W1t,   short* __restrict__ W2t,
    const float* __restrict__ x, float* __restrict__ sumf,
    short* __restrict__ x16)
{
  if (blockIdx.x >= 3072) {             // cast path
    int i = (blockIdx.x - 3072) * 256 + threadIdx.x;
    float v = x[i];
    sumf[i] = v;
    x16[i]  = f2bf(v);
    return;
  }
  int gw   = blockIdx.x * 4 + (threadIdx.x >> 6);
  int lane = threadIdx.x & 63;
  int l = gw / 6144;
  int g = gw % 6144;
  const float* src; short* dst; int K, N, gi;
  if (g < 2048) {                       // Wq,Wk,Wv,Wo  (512x512 each)
    int w = g >> 9; gi = g & 511; K = 512; N = 512;
    src = (w == 0 ? Wq : w == 1 ? Wk : w == 2 ? Wv : Wo) + l * 262144;
    dst = (w < 3) ? (Wqkvt + l * 786432 + w * 262144) : (Wot + l * 262144);
  } else if (g < 4096) {                // W1 (512 x 2048)
    gi = g - 2048; K = 512; N = 2048;
    src = W1 + l * 1048576; dst = W1t + l * 1048576;
  } else {                              // W2 (2048 x 512)
    gi = g - 4096; K = 2048; N = 512;
    src = W2 + l * 1048576; dst = W2t + l * 1048576;
  }
  int nb = N >> 6;
  int n  = (gi % nb) * 64 + lane;
  int k0 = (gi / nb) * 8;
  s16x8 v;
  #pragma unroll
  for (int i = 0; i < 8; i++) v[i] = f2bf(src[(size_t)(k0 + i) * N + n]);
  *(s16x8*)(dst + (size_t)n * K + k0) = v;
}

// ---------------------------------------------------------------------------
// Fused split-K reduce + LayerNorm(s). One wave per row (D=512, 8/lane).
// t = sum_{p<KS}(bf16 parts[p]) + bias + resid (rf f32 | rb bf16)
// mode 0 (O-proj): sumf = t          ; outb = bf16(LN(t))
// mode 1 (FFN2 L0): sumf = LN(t)     ; outb = bf16(LN(t))
// mode 2 (FFN2 L1): outf32 = LNf(LN2(t))   (final output, f32)
// ---------------------------------------------------------------------------
__global__ __launch_bounds__(256) void skred_ln(
    const short* __restrict__ parts, const float* __restrict__ bias,
    const float* __restrict__ rf, const short* __restrict__ rb,
    const float* __restrict__ g, const float* __restrict__ bb,
    const float* __restrict__ g2, const float* __restrict__ bb2,
    float* __restrict__ sumf, short* __restrict__ outb,
    float* __restrict__ outf32, int KS, int mode)
{
  const int row  = blockIdx.x * 4 + (threadIdx.x >> 6);
  const int lane = threadIdx.x & 63;
  const int col  = lane * 8;
  const size_t base = (size_t)row * DM + col;
  float t[8];
  #pragma unroll
  for (int j = 0; j < 8; j++) t[j] = bias[col + j];
  #pragma unroll 4
  for (int p = 0; p < KS; p++) {
    s16x8 v = *(const s16x8*)(parts + (size_t)p * (NTOK * DM) + base);
    #pragma unroll
    for (int j = 0; j < 8; j++) t[j] += bf2f(v[j]);
  }
  if (mode == 0) {
    #pragma unroll
    for (int j = 0; j < 8; j++) t[j] += rf[base + j];
  } else {
    s16x8 v = *(const s16x8*)(rb + base);
    #pragma unroll
    for (int j = 0; j < 8; j++) t[j] += bf2f(v[j]);
  }
  float s = 0.f, ss = 0.f;
  #pragma unroll
  for (int j = 0; j < 8; j++) { s += t[j]; ss += t[j] * t[j]; }
  #pragma unroll
  for (int off = 32; off > 0; off >>= 1) {
    s += __shfl_xor(s, off); ss += __shfl_xor(ss, off);
  }
  float mean = s * (1.f / DM);
  float var  = ss * (1.f / DM) - mean * mean;
  float rstd = rsqrtf(var + 1e-5f);
  if (mode == 0) {
    #pragma unroll
    for (int j = 0; j < 8; j++) {
      sumf[base + j] = t[j];
      outb[base + j] = f2bf((t[j] - mean) * rstd * g[col + j] + bb[col + j]);
    }
  } else if (mode == 1) {
    #pragma unroll
    for (int j = 0; j < 8; j++) {
      float y = (t[j] - mean) * rstd * g[col + j] + bb[col + j];
      sumf[base + j] = y;
      outb[base + j] = f2bf(y);
    }
  } else {                              // mode 2: LN2 then LNf, f32 out
    float y[8]; float s2 = 0.f, ss2 = 0.f;
    #pragma unroll
    for (int j = 0; j < 8; j++) {
      y[j] = (t[j] - mean) * rstd * g[col + j] + bb[col + j];
      s2 += y[j]; ss2 += y[j] * y[j];
    }
    #pragma unroll
    for (int off = 32; off > 0; off >>= 1) {
      s2 += __shfl_xor(s2, off); ss2 += __shfl_xor(ss2, off);
    }
    float mean2 = s2 * (1.f / DM);
    float var2  = ss2 * (1.f / DM) - mean2 * mean2;
    float rstd2 = rsqrtf(var2 + 1e-5f);
    #pragma unroll
    for (int j = 0; j < 8; j++)
      outf32[base + j] = (y[j] - mean2) * rstd2 * g2[col + j] + bb2[col + j];
  }
}

// ---------------------------------------------------------------------------
// GEMM: C(M,N) = A(M,K) @ W, W pre-transposed Bt(N,K). bf16 MFMA.
// Tile TM x 128, BK=64 staged as two stride-32 halves per barrier pair
// (round-16 harness-proven structure). Optional split-K.
// Modes: 0=QKV scatter, 2=GELU->bf16, 4=bf16 partial write.
// ---------------------------------------------------------------------------
template<int TM>
__global__ __launch_bounds__(256) void gemm_bt(
    const short* __restrict__ A, const short* __restrict__ Bt,
    int M, int N, int K, int KS, int mode,
    const float* __restrict__ bq, const float* __restrict__ bk,
    const float* __restrict__ bv,
    short* __restrict__ oq, short* __restrict__ okk, short* __restrict__ ov)
{
  __shared__ short As[2][TM * 32];     // two K-halves, proven layout each
  __shared__ short Bs[2][128 * 32];
  constexpr int MT = TM / 32;          // 16-row tiles per wave (4 or 2)
  const int tid  = threadIdx.x;
  const int lane = tid & 63;
  const int wid  = tid >> 6;
  const int lm   = lane & 15, quad = lane >> 4;
  const int nbn  = N >> 7;
  const int nb2  = (M / TM) * nbn;
  const int ks   = blockIdx.x / nb2;
  const int rem  = blockIdx.x % nb2;
  const int m0   = (rem / nbn) * TM;
  const int n0   = (rem % nbn) << 7;
  const int wm   = (wid & 1) * (TM / 2), wn = (wid >> 1) * 64;
  const int Kc   = K / KS;
  const int kbeg = ks * Kc;

  f32x4 acc[MT][4];
  #pragma unroll
  for (int i = 0; i < MT; i++)
    #pragma unroll
    for (int j = 0; j < 4; j++) acc[i][j] = (f32x4){0.f, 0.f, 0.f, 0.f};

  const short* Abase = A  + (size_t)m0 * K;
  const short* Bbase = Bt + (size_t)n0 * K;

  for (int k0 = kbeg; k0 < kbeg + Kc; k0 += 64) {
    __syncthreads();                     // prior iteration's LDS reads done
    #pragma unroll
    for (int half = 0; half < 2; half++) {
      const int kk = k0 + half * 32;
      #pragma unroll
      for (int j = 0; j < TM / 64; j++) {  // As half: TM*4 chunks of 16B
        int c = j * 256 + wid * 64 + lane;
        gl_lds16(Abase + (size_t)(c >> 2) * K + kk + (c & 3) * 8,
                 &As[half][(j * 256 + wid * 64) * 8]);
      }
      #pragma unroll
      for (int j = 0; j < 2; j++) {        // Bs half: 512 chunks
        int c = j * 256 + wid * 64 + lane;
        gl_lds16(Bbase + (size_t)(c >> 2) * K + kk + (c & 3) * 8,
                 &Bs[half][(j * 256 + wid * 64) * 8]);
      }
    }
    __syncthreads();                     // drains vmcnt -> tiles in LDS
    #pragma unroll
    for (int half = 0; half < 2; half++) {
      bf16x8 af[MT], bfr[4];
      #pragma unroll
      for (int t = 0; t < MT; t++)
        af[t] = *(const bf16x8*)&As[half][(wm + t * 16 + lm) * 32 + quad * 8];
      #pragma unroll
      for (int t = 0; t < 4; t++)
        bfr[t] = *(const bf16x8*)&Bs[half][(wn + t * 16 + lm) * 32 + quad * 8];
      #pragma unroll
      for (int mt = 0; mt < MT; mt++)
        #pragma unroll
        for (int nt = 0; nt < 4; nt++)
          acc[mt][nt] = mfma16(af[mt], bfr[nt], acc[mt][nt]);
    }
  }

  #pragma unroll
  for (int mt = 0; mt < MT; mt++) {
    int row = m0 + wm + mt * 16 + quad * 4;
    #pragma unroll
    for (int nt = 0; nt < 4; nt++) {
      int col = n0 + wn + nt * 16 + lm;
      f32x4 v = acc[mt][nt];
      if (mode == 0) {                       // QKV scatter, N=1536
        int which = col >> 9; int d = col & 511;
        int hh = d >> 6; int e = d & 63;
        const float* bias = which == 0 ? bq : which == 1 ? bk : bv;
        float bb = bias[d];
        #pragma unroll
        for (int r = 0; r < 4; r++) {
          int tok = row + r; int bI = tok >> 11, li = tok & 2047;
          float val = v[r] + bb;
          if (which == 0)
            oq [(((size_t)bI * NH + hh) * SEQ + li) * EH + e] = f2bf(val);
          else if (which == 1)
            okk[(((size_t)bI * NH + hh) * SEQ + li) * EH + e] = f2bf(val);
          else
            ov [(((size_t)bI * NH + hh) * EH + e) * SEQ + li] = f2bf(val);
        }
      } else if (mode == 2) {                // GELU -> bf16
        float bb = bq[col];
        #pragma unroll
        for (int r = 0; r < 4; r++) {
          float x = v[r] + bb;
          float u = 0.7978845608f * (x + 0.044715f * x * x * x);
          float t = 1.f - 2.f / (1.f + __expf(2.f * u));   // tanh, safe
          size_t idx = (size_t)(row + r) * N + col;
          oq[idx] = f2bf(0.5f * x * (1.f + t));
        }
      } else {                               // mode 4: bf16 split-K partial
        short* op = oq + (size_t)ks * M * N;
        #pragma unroll
        for (int r = 0; r < 4; r++)
          op[(size_t)(row + r) * N + col] = f2bf(v[r]);
      }
    }
  }
}

// ---------------------------------------------------------------------------
// Attention subtile (round-17 harness-verified): QK^T (16q x 64k) ->
// fixed-bias softmax (truncated P, l from truncated values) -> PV accumulate.
// ---------------------------------------------------------------------------
__device__ __forceinline__ void do_subtile(
    bf16x8 qf0, bf16x8 qf1,
    const short* __restrict__ Ks, const short* __restrict__ Vs,
    short* __restrict__ Psw, const float* dl, float st2,
    int s0, int rowq0, bool diag,
    float* lr, f32x4* O, int lm, int quad)
{
  f32x4 S[4];
  #pragma unroll
  for (int nt = 0; nt < 4; nt++) {
    S[nt] = (f32x4){0.f, 0.f, 0.f, 0.f};
    S[nt] = mfma16(qf0, *(const bf16x8*)&Ks[(nt*16 + lm) * 72 + quad * 8], S[nt]);
    S[nt] = mfma16(qf1, *(const bf16x8*)&Ks[(nt*16 + lm) * 72 + 32 + quad * 8], S[nt]);
  }
  #pragma unroll
  for (int r = 0; r < 4; r++) {
    float sc[4];
    #pragma unroll
    for (int nt = 0; nt < 4; nt++) sc[nt] = fmaf(st2, S[nt][r], dl[nt]);
    if (diag) {
      int rowq = rowq0 + quad * 4 + r;
      #pragma unroll
      for (int nt = 0; nt < 4; nt++)
        if (s0 + nt * 16 + lm > rowq) sc[nt] = -__builtin_inff();
    }
    unsigned int u0 = __float_as_uint(exp2f(sc[0]));
    unsigned int u1 = __float_as_uint(exp2f(sc[1]));
    unsigned int u2 = __float_as_uint(exp2f(sc[2]));
    unsigned int u3 = __float_as_uint(exp2f(sc[3]));
    lr[r] += (__uint_as_float(u0 & 0xffff0000u) +
              __uint_as_float(u1 & 0xffff0000u)) +
             (__uint_as_float(u2 & 0xffff0000u) +
              __uint_as_float(u3 & 0xffff0000u));
    short* pr = &Psw[(quad * 4 + r) * 72];
    pr[lm]      = (short)(u0 >> 16);
    pr[16 + lm] = (short)(u1 >> 16);
    pr[32 + lm] = (short)(u2 >> 16);
    pr[48 + lm] = (short)(u3 >> 16);
  }
  bf16x8 pf0 = *(const bf16x8*)&Psw[lm * 72 + quad * 8];
  bf16x8 pf1 = *(const bf16x8*)&Psw[lm * 72 + 32 + quad * 8];
  #pragma unroll
  for (int et = 0; et < 4; et++) {
    O[et] = mfma16(pf0, *(const bf16x8*)&Vs[(et*16 + lm) * 72 + quad * 8], O[et]);
    O[et] = mfma16(pf1, *(const bf16x8*)&Vs[(et*16 + lm) * 72 + 32 + quad * 8], O[et]);
  }
}

// ---------------------------------------------------------------------------
// Flash attention v9 = v7c (XCD swizzle, fixed-bias softmax, 4-way key
// split) + PAIRED 64-key staging: two K/V tiles per barrier pair, halving
// barrier count per key-block. Inner math = round-17-verified do_subtile.
// ---------------------------------------------------------------------------
__global__ __launch_bounds__(256) void attn_v9(
    const short* __restrict__ Q, const short* __restrict__ Kg,
    const short* __restrict__ Vt,
    const float* __restrict__ tau, const float* __restrict__ delta,
    short* __restrict__ opart, float* __restrict__ lpart)
{
  __shared__ short Ks[2][64 * 72];    // two staged key-tiles [key][e]
  __shared__ short Vs[2][64 * 72];    // [e][key]
  __shared__ short Ps[4][16 * 72];    // per-wave P scratch [q][key]
  const int tid  = threadIdx.x;
  const int lane = tid & 63, wid = tid >> 6;
  const int lm = lane & 15, quad = lane >> 4;
  const int blk   = blockIdx.x;
  const int bh    = blk & 15;         // XCD swizzle: %16 = bh
  const int rest  = blk >> 4;
  const int part  = rest & 3;         // key quarter
  const int qbrev = rest >> 2;        // 0 = most work (qb=31) first
  const int qb = 31 - qbrev;
  const int b  = bh >> 3;
  const int q0 = qb * 64;
  const int qw = q0 + wid * 16;
  const int t_lin = bh * 32 + qbrev;  // tile id for partial slots
  const size_t bhq = (size_t)bh * SEQ;
  const short* kbase = Kg + bhq * EH;
  const short* vbase = Vt + (size_t)bh * (EH * SEQ);

  const int nblk = qb + 1;
  const int kb0 = (nblk * part) >> 2;
  const int kb1 = (nblk * (part + 1)) >> 2;

  bf16x8 qf0 = *(const bf16x8*)(Q + (bhq + qw + lm) * EH + quad * 8);
  bf16x8 qf1 = *(const bf16x8*)(Q + (bhq + qw + lm) * EH + 32 + quad * 8);

  const float st2 = 0.125f * LOG2E * tau[b];
  f32x4 O[4];
  #pragma unroll
  for (int i = 0; i < 4; i++) O[i] = (f32x4){0.f, 0.f, 0.f, 0.f};
  float lr[4] = {0.f, 0.f, 0.f, 0.f};   // per-lane partial row sums

  const int r0 = tid >> 3,         ch0 = (tid & 7) * 8;
  const int r1 = (tid + 256) >> 3, ch1 = (tid & 7) * 8;

  for (int kb = kb0; kb < kb1; ) {
    const int n = (kb1 - kb >= 2) ? 2 : 1;   // block-uniform
    s16x8 kr0[2], kr1[2], vr0[2], vr1[2];
    #pragma unroll
    for (int j = 0; j < 2; j++) if (j < n) {
      const int s0 = (kb + j) << 6;
      kr0[j] = *(const s16x8*)(kbase + (size_t)(s0 + r0) * EH + ch0);
      kr1[j] = *(const s16x8*)(kbase + (size_t)(s0 + r1) * EH + ch1);
      vr0[j] = *(const s16x8*)(vbase + (size_t)r0 * SEQ + s0 + ch0);
      vr1[j] = *(const s16x8*)(vbase + (size_t)r1 * SEQ + s0 + ch1);
    }
    __syncthreads();                  // prior stage's LDS reads done
    #pragma unroll
    for (int j = 0; j < 2; j++) if (j < n) {
      *(s16x8*)&Ks[j][r0 * 72 + ch0] = kr0[j];
      *(s16x8*)&Ks[j][r1 * 72 + ch1] = kr1[j];
      *(s16x8*)&Vs[j][r0 * 72 + ch0] = vr0[j];
      *(s16x8*)&Vs[j][r1 * 72 + ch1] = vr1[j];
    }
    __syncthreads();
    #pragma unroll
    for (int j = 0; j < 2; j++) if (j < n) {
      const int s0 = (kb + j) << 6;
      float dl[4];
      #pragma unroll
      for (int nt = 0; nt < 4; nt++)
        dl[nt] = fmaf(0.125f * LOG2E,
                      delta[(size_t)b * SEQ + s0 + nt * 16 + lm], -8.f);
      do_subtile(qf0, qf1, Ks[j], Vs[j], Ps[wid], dl, st2, s0, qw,
                 (kb + j) == qb, lr, O, lm, quad);
    }
    kb += n;
  }

  // Reduce lr across the 16 lanes of each row group (once).
  #pragma unroll
  for (int r = 0; r < 4; r++) {
    float s = lr[r];
    #pragma unroll
    for (int off = 1; off < 16; off <<= 1) s += __shfl_xor(s, off);
    lr[r] = s;
  }

  // Write partials: O (bf16) to opart[slot], l (f32) to lpart[slot].
  const int slot = ((t_lin << 2) | part);
  short* ob = opart + (size_t)slot * 4096;
  float* lb = lpart + (size_t)slot * 64;
  #pragma unroll
  for (int r = 0; r < 4; r++) {
    int qloc = wid * 16 + quad * 4 + r;
    #pragma unroll
    for (int et = 0; et < 4; et++)
      ob[qloc * 64 + et * 16 + lm] = f2bf(O[et][r]);
    if (lm == 0) lb[qloc] = lr[r];
  }
}

// Combine the 4 key-quarter partials, normalize, write bf16 at16 (B*L, D).
__global__ __launch_bounds__(256) void attn_reduce(
    const short* __restrict__ opart, const float* __restrict__ lpart,
    short* __restrict__ Oa)
{
  const int t = blockIdx.x;           // tile id (v7b slot mapping)
  const int qb = 31 - (t & 31);
  const int h  = (t >> 5) & 7;
  const int b  = t >> 8;
  const int q0 = qb * 64;
  #pragma unroll
  for (int i = 0; i < 16; i++) {
    int idx = i * 256 + threadIdx.x;
    int q = idx >> 6, e = idx & 63;
    float l = 0.f, o = 0.f;
    #pragma unroll
    for (int p = 0; p < 4; p++) {
      int slot = t * 4 + p;
      l += lpart[(size_t)slot * 64 + q];
      o += bf2f(opart[(size_t)slot * 4096 + idx]);
    }
    Oa[((size_t)b * SEQ + q0 + q) * DM + h * EH + e] = f2bf(o / l);
  }
}

// ---------------------------------------------------------------------------
extern "C" void kernel_launch(void* const* d_in, const int* in_sizes, int n_in,
                              void* d_out, int out_size, void* d_ws, size_t ws_size,
                              hipStream_t stream)
{
  float* out = (float*)d_out;          // f32 output

  if (ws_size < (size_t)62918656) {    // 60 MB + safety
    fill_code_f32<<<2097152 / 256, 256, 0, stream>>>(
        out, 1200.f + (float)(ws_size >> 20));
    return;
  }

  const float* x    = (const float*)d_in[0];
  const float* tau  = (const float*)d_in[1];
  const float* del  = (const float*)d_in[2];
  const float* Wq = (const float*)d_in[4];
  const float* bq = (const float*)d_in[5];
  const float* Wk = (const float*)d_in[6];
  const float* bk = (const float*)d_in[7];
  const float* Wv = (const float*)d_in[8];
  const float* bv = (const float*)d_in[9];
  const float* Wo = (const float*)d_in[10];
  const float* bo = (const float*)d_in[11];
  const float* W1 = (const float*)d_in[12];
  const float* b1 = (const float*)d_in[13];
  const float* W2 = (const float*)d_in[14];
  const float* b2 = (const float*)d_in[15];
  const float* ln1g = (const float*)d_in[16];
  const float* ln1b = (const float*)d_in[17];
  const float* ln2g = (const float*)d_in[18];
  const float* ln2b = (const float*)d_in[19];
  const float* lnfg = (const float*)d_in[20];
  const float* lnfb = (const float*)d_in[21];

  char* ws = (char*)d_ws;
  float* sumf  = (float*)(ws + 0);          //  8 MB  fp32 residual chain (x)
  short* x16   = (short*)(ws + 8388608);    //  4 MB  bf16 x (GEMM A operand)
  short* xb16  = (short*)(ws + 12582912);   //  4 MB  LN1 out (xb)
  short* q16   = (short*)(ws + 16777216);   //  4 MB  (B,H,L,E)
  short* k16   = (short*)(ws + 20971520);   //  4 MB  (B,H,L,E)
  short* vt16  = (short*)(ws + 25165824);   //  4 MB  (B,H,E,L)
  short* at16  = (short*)(ws + 29360128);   //  4 MB  attention out (B*L, D)
  short* h16   = (short*)(ws + 33554432);   // 16 MB  FFN hidden
  short* Wqkvt = (short*)(ws + 50331648);   //  3 MB
  short* Wot   = (short*)(ws + 53477376);   //  1 MB
  short* W1t   = (short*)(ws + 54525952);   //  4 MB
  short* W2t   = (short*)(ws + 58720256);   //  4 MB  (total 60 MB)
  // Overlays (regions dead at time of use):
  short* aopart = (short*)(ws + 33554432);  // attn O partials (h16, 16 MB)
  float* alpart = (float*)(ws + 12582912);  // attn l partials (xb16, 512 KB)
  short* oppart = (short*)(ws + 33554432);  // O-proj split-K partials (h16)
  short* f2part = (short*)(ws + 16777216);  // FFN2 split-K partials
                                            //   (q16..at16, 16 MB)

  prep_all<<<11264, 256, 0, stream>>>(Wq, Wk, Wv, Wo, W1, W2,
                                      Wqkvt, Wot, W1t, W2t, x, sumf, x16);

  for (int l = 0; l < 2; l++) {
    // QKV (N=1536, K=512) -- TM=64: 768 blocks, 8 BK=64 iters
    gemm_bt<64><<<64 * 12, 256, 0, stream>>>(x16, Wqkvt + l * 786432,
        NTOK, 3 * DM, DM, 1, 0,
        bq + l * DM, bk + l * DM, bv + l * DM,
        q16, k16, vt16);
    attn_v9<<<4 * NBAT * NH * (SEQ / 64), 256, 0, stream>>>(
        q16, k16, vt16, tau, del, aopart, alpart);
    attn_reduce<<<NBAT * NH * (SEQ / 64), 256, 0, stream>>>(
        aopart, alpart, at16);
    // O-proj: split-K x2 -> fused reduce + residual + LN1 (xb16)
    gemm_bt<64><<<64 * 4 * 2, 256, 0, stream>>>(at16, Wot + l * 262144,
        NTOK, DM, DM, 2, 4,
        nullptr, nullptr, nullptr,
        oppart, nullptr, nullptr);
    skred_ln<<<1024, 256, 0, stream>>>(oppart, bo + l * DM, sumf, nullptr,
        ln1g + l * DM, ln1b + l * DM, nullptr, nullptr,
        sumf, xb16, nullptr, 2, 0);
    // FFN1 + GELU (N=2048, K=512) -- TM=64: 1024 blocks, 8 BK=64 iters
    gemm_bt<64><<<64 * 16, 256, 0, stream>>>(xb16, W1t + l * 1048576,
        NTOK, DFF, DM, 1, 2,
        b1 + l * DFF, nullptr, nullptr,
        h16, nullptr, nullptr);
    // FFN2: split-K x4 -> fused reduce + xb residual + LN2 (+LNf on l==1)
    gemm_bt<64><<<64 * 4 * 4, 256, 0, stream>>>(h16, W2t + l * 1048576,
        NTOK, DM, DFF, 4, 4,
        nullptr, nullptr, nullptr,
        f2part, nullptr, nullptr);
    if (l == 0) {
      skred_ln<<<1024, 256, 0, stream>>>(f2part, b2 + l * DM, nullptr, xb16,
          ln2g + l * DM, ln2b + l * DM, nullptr, nullptr,
          sumf, x16, nullptr, 4, 1);
    } else {
      // Fused LN2 + final LNf -> f32 output
      skred_ln<<<1024, 256, 0, stream>>>(f2part, b2 + l * DM, nullptr, xb16,
          ln2g + l * DM, ln2b + l * DM, lnfg, lnfb,
          nullptr, nullptr, out, 4, 2);
    }
  }
}